// Round 10
// baseline (540.931 us; speedup 1.0000x reference)
//
#include <hip/hip_runtime.h>
#include <stdint.h>

typedef int v4i __attribute__((ext_vector_type(4)));
typedef short v8s __attribute__((ext_vector_type(8)));
#define DEV __device__ __forceinline__

constexpr int NS    = 1024;
constexpr int NHID  = 2048;
constexpr int NHEAD = 16;
constexpr int NKVH  = 4;
constexpr int ND    = 128;
constexpr int NC    = 4096;
constexpr int NKV   = 512;

#define SL_X 0
#define SL_WQ 1
#define SL_WK 2
#define SL_WV 3
#define SL_WO 4
#define SL_Q 5
#define SL_K 6
#define SL_QH1 7
#define SL_QH2 8
#define SL_KH1 9
#define SL_KH2 10
#define SL_QA 11
#define SL_QB 12
#define SL_KA 13
#define SL_KB 14
#define SL_QEMB 15
#define SL_KEMB 16
#define SL_CKT 17
#define SL_CVT 18
#define SL_VLIN 19
#define SL_LAM 20
#define SL_MINSUM 21
#define SL_OATT 22

__device__ float g_slots[64];
__device__ int   g_rowsumQ[NHEAD * NS];
__device__ float g_LmaxP[128][NHEAD * NS];
__device__ float g_LsP[128][NHEAD * NS];
__device__ float g_Lmax[NHEAD * NS];
__device__ float g_Lsum[NHEAD * NS];
__device__ int   g_colsumV[NKVH * ND];
__device__ __align__(16) int8_t g_Xq[NS * NHID];
__device__ __align__(16) int8_t g_W1q[NHID * NHID];
__device__ __align__(16) int8_t g_Woq[NHID * NHID];
__device__ __align__(16) int8_t g_Wkq[NKV * NHID];
__device__ __align__(16) int8_t g_Wvq[NKV * NHID];
__device__ __align__(16) float  g_qlin[NS * NHID];
__device__ __align__(16) int8_t g_q8[NHEAD * NS * ND];
__device__ __align__(16) int8_t g_khi[NKVH * NC * ND];
__device__ __align__(16) int8_t g_klo[NKVH * NC * ND];
__device__ __align__(16) int8_t g_vT[NKVH * ND * NC];
__device__ __align__(16) int8_t g_Oq[NS * NHID];
// int16 logit codes, tiled [h][cb=64][s=1024][64 cols]
__device__ __align__(16) unsigned short g_L16[NHEAD * 64 * NS * 64];

DEV float sc8(float a)  { return fmaxf(a, 1e-8f) / 127.0f; }
DEV float sc16(float a) { return fmaxf(a, 1e-8f) / 32767.0f; }

DEV float fq_vali(float x, float s, float invs, float qmax) {
  float q = rintf(x * invs);
  q = fminf(fmaxf(q, -qmax - 1.0f), qmax);
  return q * s;
}
DEV float fq_inti(float x, float invs, float qmax) {
  float q = rintf(x * invs);
  return fminf(fmaxf(q, -qmax - 1.0f), qmax);
}

DEV float block_reduce_max(float m) {
  #pragma unroll
  for (int o = 32; o > 0; o >>= 1) m = fmaxf(m, __shfl_down(m, o, 64));
  __shared__ float red[4];
  __syncthreads();
  if ((threadIdx.x & 63) == 0) red[threadIdx.x >> 6] = m;
  __syncthreads();
  return fmaxf(fmaxf(red[0], red[1]), fmaxf(red[2], red[3]));
}

__global__ void k_init() {
  int t = threadIdx.x;
  if (t < 64) g_slots[t] = (t == SL_MINSUM) ? __builtin_inff() : 0.0f;
  g_colsumV[t] = 0;
  g_colsumV[t + 256] = 0;
}

// ---------- fused absmax over 5 raw inputs + cache tails ----------
DEV void absmax_part(const float* __restrict__ in, int n4, int slot, int b0, int nb) {
  float m = 0.0f;
  int stride = nb * 256;
  for (int i = b0 * 256 + threadIdx.x; i < n4; i += stride) {
    float4 v = ((const float4*)in)[i];
    m = fmaxf(m, fmaxf(fmaxf(fabsf(v.x), fabsf(v.y)), fmaxf(fabsf(v.z), fabsf(v.w))));
  }
  m = block_reduce_max(m);
  if (threadIdx.x == 0) atomicMax((unsigned int*)&g_slots[slot], __float_as_uint(m));
}
DEV void absmax_cache_part(const float* __restrict__ src, int slot, int b0, int nb) {
  float m = 0.0f;
  int stride = nb * 256;
  const int n4 = NKVH * 3072 * 32;
  for (int i = b0 * 256 + threadIdx.x; i < n4; i += stride) {
    int d4 = (i & 31) << 2;
    int rc = i >> 5;
    int kvh = rc / 3072, rr = rc - kvh * 3072;
    float4 v = *(const float4*)(src + kvh * (NC * ND) + (1024 + rr) * ND + d4);
    m = fmaxf(m, fmaxf(fmaxf(fabsf(v.x), fabsf(v.y)), fmaxf(fabsf(v.z), fabsf(v.w))));
  }
  m = block_reduce_max(m);
  if (threadIdx.x == 0) atomicMax((unsigned int*)&g_slots[slot], __float_as_uint(m));
}
__global__ __launch_bounds__(256) void k_absmax7(const float* x, const float* wq,
                                                 const float* wk, const float* wv,
                                                 const float* wo, const float* ck,
                                                 const float* cv) {
  int b = blockIdx.x;
  if      (b < 512)  absmax_part(x,  NS*NHID/4,   SL_X,  b,        512);
  else if (b < 1536) absmax_part(wq, NHID*NHID/4, SL_WQ, b - 512,  1024);
  else if (b < 2048) absmax_part(wk, NKV*NHID/4,  SL_WK, b - 1536, 512);
  else if (b < 2560) absmax_part(wv, NKV*NHID/4,  SL_WV, b - 2048, 512);
  else if (b < 3584) absmax_part(wo, NHID*NHID/4, SL_WO, b - 2560, 1024);
  else if (b < 4096) absmax_cache_part(ck, SL_CKT, b - 3584, 512);
  else               absmax_cache_part(cv, SL_CVT, b - 4096, 512);
}

// ---------- fused quantize of x + 4 weights ----------
DEV void quant_part(const float* __restrict__ in, int8_t* __restrict__ out,
                    int n4, int slot, int b0, int nb) {
  float s = sc8(g_slots[slot]);
  float is = 1.0f / s;
  int stride = nb * 256;
  for (int i = b0 * 256 + threadIdx.x; i < n4; i += stride) {
    float4 v = ((const float4*)in)[i];
    char4 q = make_char4((signed char)(int)fq_inti(v.x, is, 127.f),
                         (signed char)(int)fq_inti(v.y, is, 127.f),
                         (signed char)(int)fq_inti(v.z, is, 127.f),
                         (signed char)(int)fq_inti(v.w, is, 127.f));
    ((char4*)out)[i] = q;
  }
}
__global__ __launch_bounds__(256) void k_quant5(const float* x, const float* wq,
                                                const float* wk, const float* wv,
                                                const float* wo) {
  int b = blockIdx.x;
  if      (b < 512)  quant_part(x,  g_Xq,  NS*NHID/4,   SL_X,  b,        512);
  else if (b < 1536) quant_part(wq, g_W1q, NHID*NHID/4, SL_WQ, b - 512,  1024);
  else if (b < 2048) quant_part(wk, g_Wkq, NKV*NHID/4,  SL_WK, b - 1536, 512);
  else if (b < 2560) quant_part(wv, g_Wvq, NKV*NHID/4,  SL_WV, b - 2048, 512);
  else               quant_part(wo, g_Woq, NHID*NHID/4, SL_WO, b - 2560, 1024);
}
__global__ __launch_bounds__(256) void k_quant8_oatt() {
  quant_part(g_qlin, g_Oq, NS*NHID/4, SL_OATT, blockIdx.x, 512);
}

// ---------- int8 GEMM with fused output absmax ----------
DEV void gemm_body(const int8_t* __restrict__ A, const int8_t* __restrict__ B,
                   const float* __restrict__ bias, float* __restrict__ C,
                   int N, int K, int sa, int sb, int outslot) {
  float scale = sc8(g_slots[sa]) * sc8(g_slots[sb]);
  int wave = threadIdx.x >> 6, lane = threadIdx.x & 63;
  int r = lane & 15, kg = lane >> 4;
  int m0 = blockIdx.y * 64 + wave * 16;
  int n0 = blockIdx.x * 64;
  const int8_t* ap = A + (m0 + r) * K + kg * 16;
  const int8_t* bp = B + (n0 + r) * K + kg * 16;
  v4i acc[4] = {{0,0,0,0},{0,0,0,0},{0,0,0,0},{0,0,0,0}};
  for (int kb = 0; kb < K; kb += 64) {
    v4i a = *(const v4i*)(ap + kb);
    #pragma unroll
    for (int j = 0; j < 4; j++) {
      v4i bf = *(const v4i*)(bp + j * 16 * K + kb);
      acc[j] = __builtin_amdgcn_mfma_i32_16x16x64_i8(a, bf, acc[j], 0, 0, 0);
    }
  }
  float am = 0.0f;
  #pragma unroll
  for (int j = 0; j < 4; j++) {
    int n = n0 + j * 16 + r;
    float bvf = bias ? bias[n] : 0.0f;
    #pragma unroll
    for (int t = 0; t < 4; t++) {
      int m = m0 + kg * 4 + t;
      float val = (float)acc[j][t] * scale + bvf;
      C[m * N + n] = val;
      am = fmaxf(am, fabsf(val));
    }
  }
  if (outslot >= 0) {
    am = block_reduce_max(am);
    if (threadIdx.x == 0) atomicMax((unsigned int*)&g_slots[outslot], __float_as_uint(am));
  }
}
__global__ __launch_bounds__(256) void k_gemm_q(const float* bias) {
  gemm_body(g_Xq, g_W1q, bias, g_qlin, NHID, NHID, SL_X, SL_WQ, SL_Q);
}
__global__ __launch_bounds__(256) void k_gemm_kv(const float* bias, float* C, int which) {
  gemm_body(g_Xq, which ? g_Wvq : g_Wkq, bias, C, NKV, NHID, SL_X,
            which ? SL_WV : SL_WK, which ? SL_VLIN : SL_K);
}
__global__ __launch_bounds__(256) void k_gemm_o(float* C) {
  gemm_body(g_Oq, g_Woq, nullptr, C, NHID, NHID, SL_OATT, SL_WO, -1);
}

// ---------- RoPE chain (fused q+k per stage) ----------
struct RS8 { float st, ist, st2, ist2, s2, is2, srh, isrh; };

DEV void rope_ab(const float* __restrict__ rowp, const float* __restrict__ cosp,
                 const float* __restrict__ sinp, int d4, const RS8& sc,
                 float* a, float* b) {
  float4 xv = *(const float4*)(rowp + d4);
  int pd = (d4 < 64) ? d4 + 64 : d4 - 64;
  float4 pv = *(const float4*)(rowp + pd);
  float4 cv = *(const float4*)(cosp + d4);
  float4 sv = *(const float4*)(sinp + d4);
  float xs[4] = {xv.x, xv.y, xv.z, xv.w};
  float ps[4] = {pv.x, pv.y, pv.z, pv.w};
  float cs[4] = {cv.x, cv.y, cv.z, cv.w};
  float ss[4] = {sv.x, sv.y, sv.z, sv.w};
  #pragma unroll
  for (int e = 0; e < 4; e++) {
    float v16 = fq_vali(xs[e], sc.st, sc.ist, 32767.f);
    float tp  = fq_vali(fq_vali(ps[e], sc.st, sc.ist, 32767.f), sc.st2, sc.ist2, 32767.f);
    float rh;
    if (d4 < 64) rh = fq_vali(fq_vali(-tp, sc.s2, sc.is2, 32767.f), sc.srh, sc.isrh, 32767.f);
    else         rh = fq_vali(tp, sc.srh, sc.isrh, 32767.f);
    a[e] = v16 * cs[e];
    b[e] = rh * ss[e];
  }
}

DEV RS8 mk_rsA(int slotT) {
  RS8 sc;
  sc.st = sc16(g_slots[slotT]);
  sc.ist = 1.0f / sc.st;
  sc.st2 = fmaxf(32767.f * sc.st, 1e-8f) / 32767.f;
  sc.ist2 = 1.0f / sc.st2;
  sc.s2 = 1.0f; sc.is2 = 1.0f; sc.srh = 1.0f; sc.isrh = 1.0f;
  return sc;
}
DEV RS8 mk_rs(int slotT, int slotH1, int slotH2) {
  RS8 sc;
  sc.st = sc16(g_slots[slotT]);
  sc.ist = 1.0f / sc.st;
  sc.st2 = fmaxf(32767.f * sc.st, 1e-8f) / 32767.f;
  sc.ist2 = 1.0f / sc.st2;
  sc.s2 = sc16(g_slots[slotH2]);
  sc.is2 = 1.0f / sc.s2;
  sc.srh = fmaxf(fmaxf(g_slots[slotH1], 32767.f * sc.s2), 1e-8f) / 32767.f;
  sc.isrh = 1.0f / sc.srh;
  return sc;
}

DEV void ropeA_part(const float* __restrict__ src, int nrows, const RS8& sc,
                    int sh1, int sh2, int b0, int nb) {
  int n4 = nrows * 32;
  float m1 = 0.f, m2 = 0.f;
  int stride = nb * 256;
  for (int i = b0 * 256 + threadIdx.x; i < n4; i += stride) {
    int d4 = (i & 31) << 2;
    int rowg = i >> 5;
    float4 xv = *(const float4*)(src + (rowg << 7) + d4);
    float xs[4] = {xv.x, xv.y, xv.z, xv.w};
    #pragma unroll
    for (int e = 0; e < 4; e++) {
      float t = fq_vali(fq_vali(xs[e], sc.st, sc.ist, 32767.f), sc.st2, sc.ist2, 32767.f);
      if (d4 < 64) m1 = fmaxf(m1, fabsf(t)); else m2 = fmaxf(m2, fabsf(t));
    }
  }
  m1 = block_reduce_max(m1);
  if (threadIdx.x == 0) atomicMax((unsigned int*)&g_slots[sh1], __float_as_uint(m1));
  m2 = block_reduce_max(m2);
  if (threadIdx.x == 0) atomicMax((unsigned int*)&g_slots[sh2], __float_as_uint(m2));
}

DEV void ropeBC_part(const float* __restrict__ src, const float* __restrict__ cosb,
                     const float* __restrict__ sinb, int nrows, int lgH, const RS8& sc,
                     int mode, float sa, float isa, float sb, float isb,
                     int o1, int o2, int b0, int nb) {
  int n4 = nrows * 32;
  float m1 = 0.f, m2 = 0.f;
  int stride = nb * 256;
  for (int i = b0 * 256 + threadIdx.x; i < n4; i += stride) {
    int d4 = (i & 31) << 2;
    int rowg = i >> 5;
    int s = rowg >> lgH;
    float a[4], b[4];
    rope_ab(src + (rowg << 7), cosb + (s << 7), sinb + (s << 7), d4, sc, a, b);
    if (mode == 0) {
      #pragma unroll
      for (int e = 0; e < 4; e++) { m1 = fmaxf(m1, fabsf(a[e])); m2 = fmaxf(m2, fabsf(b[e])); }
    } else {
      #pragma unroll
      for (int e = 0; e < 4; e++) {
        float ev = fq_vali(a[e], sa, isa, 32767.f) + fq_vali(b[e], sb, isb, 32767.f);
        m1 = fmaxf(m1, fabsf(ev));
      }
    }
  }
  m1 = block_reduce_max(m1);
  if (threadIdx.x == 0) atomicMax((unsigned int*)&g_slots[o1], __float_as_uint(m1));
  if (mode == 0) {
    m2 = block_reduce_max(m2);
    if (threadIdx.x == 0) atomicMax((unsigned int*)&g_slots[o2], __float_as_uint(m2));
  }
}

__global__ __launch_bounds__(256) void k_ropeA(const float* klin) {
  int b = blockIdx.x;
  if (b < 512) {
    RS8 sc = mk_rsA(SL_Q);
    ropeA_part(g_qlin, NHEAD * NS, sc, SL_QH1, SL_QH2, b, 512);
  } else {
    RS8 sc = mk_rsA(SL_K);
    ropeA_part(klin, NKVH * NS, sc, SL_KH1, SL_KH2, b - 512, 256);
  }
}
__global__ __launch_bounds__(256) void k_ropeB(const float* klin, const float* cosb, const float* sinb) {
  int b = blockIdx.x;
  if (b < 512) {
    RS8 sc = mk_rs(SL_Q, SL_QH1, SL_QH2);
    ropeBC_part(g_qlin, cosb, sinb, NHEAD * NS, 4, sc, 0, 0.f, 0.f, 0.f, 0.f, SL_QA, SL_QB, b, 512);
  } else {
    RS8 sc = mk_rs(SL_K, SL_KH1, SL_KH2);
    ropeBC_part(klin, cosb, sinb, NKVH * NS, 2, sc, 0, 0.f, 0.f, 0.f, 0.f, SL_KA, SL_KB, b - 512, 256);
  }
}
__global__ __launch_bounds__(256) void k_ropeC(const float* klin, const float* cosb, const float* sinb) {
  int b = blockIdx.x;
  if (b < 512) {
    RS8 sc = mk_rs(SL_Q, SL_QH1, SL_QH2);
    float sa = sc16(g_slots[SL_QA]), sb = sc16(g_slots[SL_QB]);
    ropeBC_part(g_qlin, cosb, sinb, NHEAD * NS, 4, sc, 1, sa, 1.0f/sa, sb, 1.0f/sb,
                SL_QEMB, 0, b, 512);
  } else {
    RS8 sc = mk_rs(SL_K, SL_KH1, SL_KH2);
    float sa = sc16(g_slots[SL_KA]), sb = sc16(g_slots[SL_KB]);
    ropeBC_part(klin, cosb, sinb, NKVH * NS, 2, sc, 1, sa, 1.0f/sa, sb, 1.0f/sb,
                SL_KEMB, 0, b - 512, 256);
  }
}

DEV void ropeD_part(const float* __restrict__ src, const float* __restrict__ cosb,
                    const float* __restrict__ sinb, int lgH, const RS8& sc,
                    float sa, float isa, float sb, float isb,
                    int isQ, float se, float ise, float isq, int b0) {
  int rowg = b0 * 8 + (threadIdx.x >> 5);
  int lane32 = threadIdx.x & 31;
  int d4 = lane32 << 2;
  int hmask = (1 << lgH) - 1;
  int h = rowg & hmask, s = rowg >> lgH;
  float a[4], b[4];
  rope_ab(src + (rowg << 7), cosb + (s << 7), sinb + (s << 7), d4, sc, a, b);
  if (isQ) {
    int rs = 0;
    signed char qb[4];
    #pragma unroll
    for (int e = 0; e < 4; e++) {
      float ev = fq_vali(a[e], sa, isa, 32767.f) + fq_vali(b[e], sb, isb, 32767.f);
      float e16 = fq_vali(ev, se, ise, 32767.f);
      float qf = fq_inti(e16, isq, 127.f);
      qb[e] = (signed char)(int)qf;
      rs += (int)qf;
    }
    *(char4*)(g_q8 + ((h << 10) + s) * ND + d4) = make_char4(qb[0], qb[1], qb[2], qb[3]);
    #pragma unroll
    for (int o = 16; o > 0; o >>= 1) rs += __shfl_down(rs, o, 32);
    if (lane32 == 0) g_rowsumQ[(h << 10) + s] = rs;
  } else {
    signed char qh[4], ql[4];
    #pragma unroll
    for (int e = 0; e < 4; e++) {
      float ev = fq_vali(a[e], sa, isa, 32767.f) + fq_vali(b[e], sb, isb, 32767.f);
      int q = (int)fq_inti(ev, isq, 32767.f);
      qh[e] = (signed char)(q >> 8);
      ql[e] = (signed char)((q & 255) - 128);
    }
    int off = (h * NC + 3072 + s) * ND + d4;
    *(char4*)(g_khi + off) = make_char4(qh[0], qh[1], qh[2], qh[3]);
    *(char4*)(g_klo + off) = make_char4(ql[0], ql[1], ql[2], ql[3]);
  }
}
__global__ __launch_bounds__(256) void k_ropeD(const float* klin, const float* cosb, const float* sinb) {
  int b = blockIdx.x;
  if (b < 2048) {
    RS8 sc = mk_rs(SL_Q, SL_QH1, SL_QH2);
    float sa = sc16(g_slots[SL_QA]), sb = sc16(g_slots[SL_QB]);
    float se = sc16(g_slots[SL_QEMB]);
    float s8 = fmaxf(32767.f * se, 1e-8f) / 127.f;
    ropeD_part(g_qlin, cosb, sinb, 4, sc, sa, 1.0f/sa, sb, 1.0f/sb,
               1, se, 1.0f/se, 1.0f/s8, b);
  } else {
    RS8 sc = mk_rs(SL_K, SL_KH1, SL_KH2);
    float sa = sc16(g_slots[SL_KA]), sb = sc16(g_slots[SL_KB]);
    float sck = fmaxf(fmaxf(g_slots[SL_KEMB], g_slots[SL_CKT]), 1e-8f) / 32767.f;
    ropeD_part(klin, cosb, sinb, 2, sc, sa, 1.0f/sa, sb, 1.0f/sb,
               0, 1.f, 1.f, 1.0f/sck, b - 2048);
  }
}

// ---------- ck tail quantize + cv transpose (+colsum) fused ----------
DEV void ck_tail_part(const float* __restrict__ cache_k, int b0, int nb) {
  float sck = fmaxf(fmaxf(g_slots[SL_KEMB], g_slots[SL_CKT]), 1e-8f) / 32767.f;
  float isck = 1.0f / sck;
  int n4 = NKVH * 3072 * 32;
  int stride = nb * 256;
  for (int i = b0 * 256 + threadIdx.x; i < n4; i += stride) {
    int d4 = (i & 31) << 2;
    int rc = i >> 5;
    int kvh = rc / 3072, rr = rc - kvh * 3072;
    float4 v = *(const float4*)(cache_k + kvh * (NC * ND) + (1024 + rr) * ND + d4);
    float xs[4] = {v.x, v.y, v.z, v.w};
    signed char qh[4], ql[4];
    #pragma unroll
    for (int e = 0; e < 4; e++) {
      int q = (int)fq_inti(xs[e], isck, 32767.f);
      qh[e] = (signed char)(q >> 8);
      ql[e] = (signed char)((q & 255) - 128);
    }
    int off = (kvh * NC + rr) * ND + d4;
    *(char4*)(g_khi + off) = make_char4(qh[0], qh[1], qh[2], qh[3]);
    *(char4*)(g_klo + off) = make_char4(ql[0], ql[1], ql[2], ql[3]);
  }
}
DEV void cvT_part(const float* __restrict__ cache_v, const float* __restrict__ vlin, int bb) {
  float scv = fmaxf(fmaxf(g_slots[SL_CVT], g_slots[SL_VLIN]), 1e-8f) / 127.f;
  float iscv = 1.0f / scv;
  int kvh = bb >> 7;
  int cblk = (bb >> 1) & 63;
  int dblk = bb & 1;
  int c0 = cblk * 64, d0 = dblk * 64;
  __shared__ int8_t tile[64][68];
  #pragma unroll 4
  for (int i = 0; i < 16; i++) {
    int cl = (threadIdx.x >> 6) * 16 + i;
    int dl = threadIdx.x & 63;
    int c = c0 + cl, d = d0 + dl;
    float v = (c < 3072) ? cache_v[kvh * (NC * ND) + (1024 + c) * ND + d]
                         : vlin[(c - 3072) * NKV + kvh * ND + d];
    tile[cl][dl] = (int8_t)(int)fq_inti(v, iscv, 127.f);
  }
  __syncthreads();
  #pragma unroll 4
  for (int i = 0; i < 16; i++) {
    int dl = (threadIdx.x >> 6) * 16 + i;
    int cl = threadIdx.x & 63;
    int8_t q = tile[cl][dl];
    g_vT[(kvh * ND + d0 + dl) * NC + c0 + cl] = q;
    int s = (int)q;
    #pragma unroll
    for (int o = 32; o > 0; o >>= 1) s += __shfl_down(s, o, 64);
    if (cl == 0) atomicAdd(&g_colsumV[kvh * ND + d0 + dl], s);
  }
}
__global__ __launch_bounds__(256) void k_ckcv(const float* cache_k, const float* cache_v,
                                              const float* vlin) {
  int b = blockIdx.x;
  if (b < 512) cvT_part(cache_v, vlin, b);
  else         ck_tail_part(cache_k, b - 512, 768);
}

// ---------- attention ----------
DEV float qk_smul() {
  float se = sc16(g_slots[SL_QEMB]);
  float s8 = fmaxf(32767.f * se, 1e-8f) / 127.f;
  float sck = fmaxf(fmaxf(g_slots[SL_KEMB], g_slots[SL_CKT]), 1e-8f) / 32767.f;
  return s8 * sck * 0.08838834764831845f;
}

// pass 1: K-in-regs, 32-col chunks (K=32 VGPR -> 6 waves/SIMD occupancy).
// block=(hg,chunk128,rowq), 4 waves = 4 q-heads. Grid 2048.
__global__ __launch_bounds__(256, 4) void k_attn1(const float* __restrict__ mask) {
  int b = blockIdx.x;
  int chunk = b & 127, rowq = (b >> 7) & 3, hg = b >> 9;
  int wave = threadIdx.x >> 6, lane = threadIdx.x & 63;
  int h = (hg << 2) + wave;
  int r = lane & 15, kg = lane >> 4;
  int kvbase = hg << 12;
  int c0 = chunk << 5;
  float smul = qk_smul();
  v4i B[2][4];
  #pragma unroll
  for (int j = 0; j < 2; j++) {
    int off = (kvbase + c0 + (j << 4) + r) * ND + (kg << 4);
    B[j][0] = *(const v4i*)(g_khi + off);
    B[j][1] = *(const v4i*)(g_khi + off + 64);
    B[j][2] = *(const v4i*)(g_klo + off);
    B[j][3] = *(const v4i*)(g_klo + off + 64);
  }
  float amax = 0.f;
  int s0 = rowq << 8;
  for (int it = 0; it < 16; it++, s0 += 16) {
    const int8_t* qp = g_q8 + ((h << 10) + s0 + r) * ND + (kg << 4);
    v4i a0 = *(const v4i*)qp, a1 = *(const v4i*)(qp + 64);
    int rs[4];
    #pragma unroll
    for (int t = 0; t < 4; t++) rs[t] = g_rowsumQ[(h << 10) + s0 + (kg << 2) + t] << 7;
    const float* mrow = mask + (s0 + (kg << 2)) * NC + c0 + r;
    float mx[4] = {-__builtin_inff(), -__builtin_inff(), -__builtin_inff(), -__builtin_inff()};
    #pragma unroll
    for (int j = 0; j < 2; j++) {
      v4i z = {0,0,0,0};
      v4i hi = __builtin_amdgcn_mfma_i32_16x16x64_i8(a0, B[j][0], z, 0, 0, 0);
      hi = __builtin_amdgcn_mfma_i32_16x16x64_i8(a1, B[j][1], hi, 0, 0, 0);
      v4i lo = __builtin_amdgcn_mfma_i32_16x16x64_i8(a0, B[j][2], z, 0, 0, 0);
      lo = __builtin_amdgcn_mfma_i32_16x16x64_i8(a1, B[j][3], lo, 0, 0, 0);
      #pragma unroll
      for (int t = 0; t < 4; t++) {
        int Li = (hi[t] << 8) + lo[t] + rs[t];
        float L = (float)Li * smul + mrow[t * NC + (j << 4)];
        mx[t] = fmaxf(mx[t], L);
        amax = fmaxf(amax, fabsf(L));
      }
    }
    #pragma unroll
    for (int o = 1; o <= 8; o <<= 1) {
      #pragma unroll
      for (int t = 0; t < 4; t++) mx[t] = fmaxf(mx[t], __shfl_xor(mx[t], o));
    }
    if (r == 0) {
      #pragma unroll
      for (int t = 0; t < 4; t++)
        g_LmaxP[chunk][(h << 10) + s0 + (kg << 2) + t] = mx[t];
    }
  }
  amax = block_reduce_max(amax);
  if (threadIdx.x == 0) atomicMax((unsigned int*)&g_slots[SL_LAM], __float_as_uint(amax));
}

// combine per-row max partials
__global__ __launch_bounds__(256) void k_rowmax() {
  int row = blockIdx.x * 256 + threadIdx.x;
  float m = -__builtin_inff();
  #pragma unroll 8
  for (int p = 0; p < 128; p++) m = fmaxf(m, g_LmaxP[p][row]);
  g_Lmax[row] = m;
}

// pass 2: K-in-regs (32-col chunks), materialize int16 codes + sum-exp partials
__global__ __launch_bounds__(256, 4) void k_attn2(const float* __restrict__ mask) {
  int b = blockIdx.x;
  int chunk = b & 127, rowq = (b >> 7) & 3, hg = b >> 9;
  int wave = threadIdx.x >> 6, lane = threadIdx.x & 63;
  int h = (hg << 2) + wave;
  int r = lane & 15, kg = lane >> 4;
  int kvbase = hg << 12;
  int c0 = chunk << 5;
  int cb = chunk >> 1;
  int colbase = (chunk & 1) << 5;
  float smul = qk_smul();
  float sL = sc16(g_slots[SL_LAM]);
  float invsL = 1.0f / sL;
  v4i B[2][4];
  #pragma unroll
  for (int j = 0; j < 2; j++) {
    int off = (kvbase + c0 + (j << 4) + r) * ND + (kg << 4);
    B[j][0] = *(const v4i*)(g_khi + off);
    B[j][1] = *(const v4i*)(g_khi + off + 64);
    B[j][2] = *(const v4i*)(g_klo + off);
    B[j][3] = *(const v4i*)(g_klo + off + 64);
  }
  int s0 = rowq << 8;
  for (int it = 0; it < 16; it++, s0 += 16) {
    const int8_t* qp = g_q8 + ((h << 10) + s0 + r) * ND + (kg << 4);
    v4i a0 = *(const v4i*)qp, a1 = *(const v4i*)(qp + 64);
    int rs[4];
    float mc[4];
    #pragma unroll
    for (int t = 0; t < 4; t++) {
      int row = (h << 10) + s0 + (kg << 2) + t;
      rs[t] = g_rowsumQ[row] << 7;
      mc[t] = fminf(fmaxf(rintf(g_Lmax[row] * invsL), -32768.f), 32767.f);
    }
    const float* mrow = mask + (s0 + (kg << 2)) * NC + c0 + r;
    unsigned short* pbase = g_L16 + (((h << 6) + cb) << 16) + ((s0 + (kg << 2)) << 6) + colbase + r;
    float sm[4] = {0.f, 0.f, 0.f, 0.f};
    #pragma unroll
    for (int j = 0; j < 2; j++) {
      v4i z = {0,0,0,0};
      v4i hi = __builtin_amdgcn_mfma_i32_16x16x64_i8(a0, B[j][0], z, 0, 0, 0);
      hi = __builtin_amdgcn_mfma_i32_16x16x64_i8(a1, B[j][1], hi, 0, 0, 0);
      v4i lo = __builtin_amdgcn_mfma_i32_16x16x64_i8(a0, B[j][2], z, 0, 0, 0);
      lo = __builtin_amdgcn_mfma_i32_16x16x64_i8(a1, B[j][3], lo, 0, 0, 0);
      #pragma unroll
      for (int t = 0; t < 4; t++) {
        int Li = (hi[t] << 8) + lo[t] + rs[t];
        float L = (float)Li * smul + mrow[t * NC + (j << 4)];
        float cf = rintf(L * invsL);
        pbase[(t << 6) + (j << 4)] = (unsigned short)(int)cf;
        sm[t] += __expf((cf - mc[t]) * sL);
      }
    }
    #pragma unroll
    for (int o = 1; o <= 8; o <<= 1) {
      #pragma unroll
      for (int t = 0; t < 4; t++) sm[t] += __shfl_xor(sm[t], o);
    }
    if (r == 0) {
      #pragma unroll
      for (int t = 0; t < 4; t++)
        g_LsP[chunk][(h << 10) + s0 + (kg << 2) + t] = sm[t];
    }
  }
}

// combine row sums (fixed order) + global min-sum
__global__ __launch_bounds__(256) void k_minsum() {
  int row = blockIdx.x * 256 + threadIdx.x;
  float sr = 0.f;
  #pragma unroll 8
  for (int p = 0; p < 128; p++) sr += g_LsP[p][row];
  g_Lsum[row] = sr;
  float m = sr;
  #pragma unroll
  for (int o = 32; o > 0; o >>= 1) m = fminf(m, __shfl_down(m, o, 64));
  __shared__ float red[4];
  __syncthreads();
  if ((threadIdx.x & 63) == 0) red[threadIdx.x >> 6] = m;
  __syncthreads();
  if (threadIdx.x == 0) {
    float v = fminf(fminf(red[0], red[1]), fminf(red[2], red[3]));
    atomicMin((unsigned int*)&g_slots[SL_MINSUM], __float_as_uint(v));
  }
}

// pass 3: P from codes -> PV (int MFMA), fused output absmax (r7 form —
// register-bound at ~124 regs/wave incl AGPR acc; structural plateau)
__global__ __launch_bounds__(256, 4) void k_attn3() {
  int h = blockIdx.x >> 6;
  int s0 = (blockIdx.x & 63) << 4;
  int wave = threadIdx.x >> 6, lane = threadIdx.x & 63;
  int r = lane & 15, kg = lane >> 4;
  int kvh = h >> 2;
  float sL = sc16(g_slots[SL_LAM]);
  float invsL = 1.0f / sL;
  float sP = fmaxf(1.0f / g_slots[SL_MINSUM], 1e-8f) / 32767.f;
  float invsP = 1.0f / sP;
  float sV = fmaxf(fmaxf(g_slots[SL_CVT], g_slots[SL_VLIN]), 1e-8f) / 127.f;
  int arow = (h << 10) + s0 + r;
  float mrc = fminf(fmaxf(rintf(g_Lmax[arow] * invsL), -32768.f), 32767.f);
  float rowscale = (1.0f / g_Lsum[arow]) * invsP;
  float Crow = __logf(rowscale) - mrc * sL;
  v4i accH[8], accL[8];
  #pragma unroll
  for (int j = 0; j < 8; j++) { accH[j] = (v4i){0,0,0,0}; accL[j] = (v4i){0,0,0,0}; }
  for (int cb = wave; cb < 64; cb += 4) {
    const unsigned short* cp = g_L16 + (((h << 6) + cb) << 16) + ((s0 + r) << 6) + kg * 16;
    v8s cA = *(const v8s*)cp;
    v8s cB = *(const v8s*)(cp + 8);
    int pq[16];
    #pragma unroll
    for (int j = 0; j < 8; j++) {
      float p = __expf((float)cA[j] * sL + Crow);
      pq[j] = (int)fminf(rintf(p), 32767.f);
    }
    #pragma unroll
    for (int j = 0; j < 8; j++) {
      float p = __expf((float)cB[j] * sL + Crow);
      pq[8 + j] = (int)fminf(rintf(p), 32767.f);
    }
    int hw[4], lw[4];
    #pragma unroll
    for (int w = 0; w < 4; w++) {
      hw[w] = (pq[4*w] >> 8) | ((pq[4*w+1] >> 8) << 8) | ((pq[4*w+2] >> 8) << 16) | ((pq[4*w+3] >> 8) << 24);
      lw[w] = ((pq[4*w] & 255) ^ 128) | (((pq[4*w+1] & 255) ^ 128) << 8)
            | (((pq[4*w+2] & 255) ^ 128) << 16) | (((pq[4*w+3] & 255) ^ 128) << 24);
    }
    v4i paH = {hw[0], hw[1], hw[2], hw[3]};
    v4i paL = {lw[0], lw[1], lw[2], lw[3]};
    #pragma unroll
    for (int j = 0; j < 8; j++) {
      v4i bv = *(const v4i*)(g_vT + (kvh * ND + j * 16 + r) * NC + cb * 64 + kg * 16);
      accH[j] = __builtin_amdgcn_mfma_i32_16x16x64_i8(paH, bv, accH[j], 0, 0, 0);
      accL[j] = __builtin_amdgcn_mfma_i32_16x16x64_i8(paL, bv, accL[j], 0, 0, 0);
    }
  }
  __shared__ int bufH[16][132];
  __shared__ int bufL[16][132];
  for (int e = threadIdx.x; e < 2048; e += 256) {
    bufH[e >> 7][e & 127] = 0;
    bufL[e >> 7][e & 127] = 0;
  }
  __syncthreads();
  #pragma unroll
  for (int j = 0; j < 8; j++) {
    #pragma unroll
    for (int t = 0; t < 4; t++) {
      atomicAdd(&bufH[kg * 4 + t][j * 16 + r], accH[j][t]);
      atomicAdd(&bufL[kg * 4 + t][j * 16 + r], accL[j][t]);
    }
  }
  __syncthreads();
  double scale = (double)sP * (double)sV;
  float am = 0.f;
  for (int e = threadIdx.x; e < 2048; e += 256) {
    int s = e >> 7, d = e & 127;
    double tot = 256.0 * (double)bufH[s][d] + (double)bufL[s][d]
               + 128.0 * (double)g_colsumV[kvh * ND + d];
    float val = (float)(tot * scale);
    g_qlin[((s0 + s) << 11) + (h << 7) + d] = val;
    am = fmaxf(am, fabsf(val));
  }
  am = block_reduce_max(am);
  if (threadIdx.x == 0) atomicMax((unsigned int*)&g_slots[SL_OATT], __float_as_uint(am));
}

extern "C" void kernel_launch(void* const* d_in, const int* in_sizes, int n_in,
                              void* d_out, int out_size, void* d_ws, size_t ws_size,
                              hipStream_t stream) {
  (void)in_sizes; (void)n_in; (void)out_size; (void)d_ws; (void)ws_size;
  const float* x      = (const float*)d_in[0];
  const float* cosb   = (const float*)d_in[1];
  const float* sinb   = (const float*)d_in[2];
  const float* cachek = (const float*)d_in[3];
  const float* cachev = (const float*)d_in[4];
  const float* mask   = (const float*)d_in[5];
  const float* Wq     = (const float*)d_in[6];
  const float* bq     = (const float*)d_in[7];
  const float* Wk     = (const float*)d_in[8];
  const float* bk     = (const float*)d_in[9];
  const float* Wv     = (const float*)d_in[10];
  const float* bv     = (const float*)d_in[11];
  const float* Wo     = (const float*)d_in[12];
  float* outO = (float*)d_out;
  float* outK = outO + NS * NHID;
  float* outV = outK + NS * NKV;

  k_init<<<1, 256, 0, stream>>>();
  k_absmax7<<<4608, 256, 0, stream>>>(x, Wq, Wk, Wv, Wo, cachek, cachev);
  k_quant5<<<3584, 256, 0, stream>>>(x, Wq, Wk, Wv, Wo);
  k_gemm_q<<<dim3(NHID / 64, NS / 64), 256, 0, stream>>>(bq);
  k_gemm_kv<<<dim3(NKV / 64, NS / 64), 256, 0, stream>>>(bk, outK, 0);
  k_gemm_kv<<<dim3(NKV / 64, NS / 64), 256, 0, stream>>>(bv, outV, 1);
  k_ropeA<<<768, 256, 0, stream>>>(outK);
  k_ropeB<<<768, 256, 0, stream>>>(outK, cosb, sinb);
  k_ropeC<<<768, 256, 0, stream>>>(outK, cosb, sinb);
  k_ropeD<<<2560, 256, 0, stream>>>(outK, cosb, sinb);
  k_ckcv<<<1280, 256, 0, stream>>>(cachek, cachev, outV);
  k_attn1<<<2048, 256, 0, stream>>>(mask);
  k_rowmax<<<64, 256, 0, stream>>>();
  k_attn2<<<2048, 256, 0, stream>>>(mask);
  k_minsum<<<64, 256, 0, stream>>>();
  k_attn3<<<1024, 256, 0, stream>>>();
  k_quant8_oatt<<<512, 256, 0, stream>>>();
  k_gemm_o<<<dim3(NHID / 64, NS / 64), 256, 0, stream>>>(outO);
}

// Round 11
// 479.444 us; speedup vs baseline: 1.1282x; 1.1282x over previous
//
#include <hip/hip_runtime.h>
#include <stdint.h>

typedef int v4i __attribute__((ext_vector_type(4)));
typedef short v8s __attribute__((ext_vector_type(8)));
#define DEV __device__ __forceinline__

constexpr int NS    = 1024;
constexpr int NHID  = 2048;
constexpr int NHEAD = 16;
constexpr int NKVH  = 4;
constexpr int ND    = 128;
constexpr int NC    = 4096;
constexpr int NKV   = 512;

#define SL_X 0
#define SL_WQ 1
#define SL_WK 2
#define SL_WV 3
#define SL_WO 4
#define SL_Q 5
#define SL_K 6
#define SL_QH1 7
#define SL_QH2 8
#define SL_KH1 9
#define SL_KH2 10
#define SL_QA 11
#define SL_QB 12
#define SL_KA 13
#define SL_KB 14
#define SL_QEMB 15
#define SL_KEMB 16
#define SL_CKT 17
#define SL_CVT 18
#define SL_VLIN 19
#define SL_LAM 20
#define SL_MINSUM 21
#define SL_OATT 22

__device__ float g_slots[64];
__device__ int   g_rowsumQ[NHEAD * NS];
__device__ float g_LmaxP[64][NHEAD * NS];
__device__ float g_LsP[64][NHEAD * NS];
__device__ float g_Lmax[NHEAD * NS];
__device__ float g_Lsum[NHEAD * NS];
__device__ int   g_colsumV[NKVH * ND];
__device__ __align__(16) int8_t g_Xq[NS * NHID];
__device__ __align__(16) int8_t g_W1q[NHID * NHID];
__device__ __align__(16) int8_t g_Woq[NHID * NHID];
__device__ __align__(16) int8_t g_Wkq[NKV * NHID];
__device__ __align__(16) int8_t g_Wvq[NKV * NHID];
__device__ __align__(16) float  g_qlin[NS * NHID];
__device__ __align__(16) int8_t g_q8[NHEAD * NS * ND];
__device__ __align__(16) int8_t g_khi[NKVH * NC * ND];
__device__ __align__(16) int8_t g_klo[NKVH * NC * ND];
__device__ __align__(16) int8_t g_vT[NKVH * ND * NC];
__device__ __align__(16) int8_t g_Oq[NS * NHID];
// int16 logit codes, tiled [h][cb=64][s=1024][64 cols] — 64-col chunks keep
// every 128B store line owned by one block (32-col chunks caused 1.7x write
// amplification, R10)
__device__ __align__(16) unsigned short g_L16[NHEAD * 64 * NS * 64];

DEV float sc8(float a)  { return fmaxf(a, 1e-8f) / 127.0f; }
DEV float sc16(float a) { return fmaxf(a, 1e-8f) / 32767.0f; }

DEV float fq_vali(float x, float s, float invs, float qmax) {
  float q = rintf(x * invs);
  q = fminf(fmaxf(q, -qmax - 1.0f), qmax);
  return q * s;
}
DEV float fq_inti(float x, float invs, float qmax) {
  float q = rintf(x * invs);
  return fminf(fmaxf(q, -qmax - 1.0f), qmax);
}

DEV float block_reduce_max(float m) {
  #pragma unroll
  for (int o = 32; o > 0; o >>= 1) m = fmaxf(m, __shfl_down(m, o, 64));
  __shared__ float red[4];
  __syncthreads();
  if ((threadIdx.x & 63) == 0) red[threadIdx.x >> 6] = m;
  __syncthreads();
  return fmaxf(fmaxf(red[0], red[1]), fmaxf(red[2], red[3]));
}

__global__ void k_init() {
  int t = threadIdx.x;
  if (t < 64) g_slots[t] = (t == SL_MINSUM) ? __builtin_inff() : 0.0f;
  g_colsumV[t] = 0;
  g_colsumV[t + 256] = 0;
}

// ---------- fused absmax over 5 raw inputs + cache tails ----------
DEV void absmax_part(const float* __restrict__ in, int n4, int slot, int b0, int nb) {
  float m = 0.0f;
  int stride = nb * 256;
  for (int i = b0 * 256 + threadIdx.x; i < n4; i += stride) {
    float4 v = ((const float4*)in)[i];
    m = fmaxf(m, fmaxf(fmaxf(fabsf(v.x), fabsf(v.y)), fmaxf(fabsf(v.z), fabsf(v.w))));
  }
  m = block_reduce_max(m);
  if (threadIdx.x == 0) atomicMax((unsigned int*)&g_slots[slot], __float_as_uint(m));
}
DEV void absmax_cache_part(const float* __restrict__ src, int slot, int b0, int nb) {
  float m = 0.0f;
  int stride = nb * 256;
  const int n4 = NKVH * 3072 * 32;
  for (int i = b0 * 256 + threadIdx.x; i < n4; i += stride) {
    int d4 = (i & 31) << 2;
    int rc = i >> 5;
    int kvh = rc / 3072, rr = rc - kvh * 3072;
    float4 v = *(const float4*)(src + kvh * (NC * ND) + (1024 + rr) * ND + d4);
    m = fmaxf(m, fmaxf(fmaxf(fabsf(v.x), fabsf(v.y)), fmaxf(fabsf(v.z), fabsf(v.w))));
  }
  m = block_reduce_max(m);
  if (threadIdx.x == 0) atomicMax((unsigned int*)&g_slots[slot], __float_as_uint(m));
}
__global__ __launch_bounds__(256) void k_absmax7(const float* x, const float* wq,
                                                 const float* wk, const float* wv,
                                                 const float* wo, const float* ck,
                                                 const float* cv) {
  int b = blockIdx.x;
  if      (b < 512)  absmax_part(x,  NS*NHID/4,   SL_X,  b,        512);
  else if (b < 1536) absmax_part(wq, NHID*NHID/4, SL_WQ, b - 512,  1024);
  else if (b < 2048) absmax_part(wk, NKV*NHID/4,  SL_WK, b - 1536, 512);
  else if (b < 2560) absmax_part(wv, NKV*NHID/4,  SL_WV, b - 2048, 512);
  else if (b < 3584) absmax_part(wo, NHID*NHID/4, SL_WO, b - 2560, 1024);
  else if (b < 4096) absmax_cache_part(ck, SL_CKT, b - 3584, 512);
  else               absmax_cache_part(cv, SL_CVT, b - 4096, 512);
}

// ---------- fused quantize of x + 4 weights ----------
DEV void quant_part(const float* __restrict__ in, int8_t* __restrict__ out,
                    int n4, int slot, int b0, int nb) {
  float s = sc8(g_slots[slot]);
  float is = 1.0f / s;
  int stride = nb * 256;
  for (int i = b0 * 256 + threadIdx.x; i < n4; i += stride) {
    float4 v = ((const float4*)in)[i];
    char4 q = make_char4((signed char)(int)fq_inti(v.x, is, 127.f),
                         (signed char)(int)fq_inti(v.y, is, 127.f),
                         (signed char)(int)fq_inti(v.z, is, 127.f),
                         (signed char)(int)fq_inti(v.w, is, 127.f));
    ((char4*)out)[i] = q;
  }
}
__global__ __launch_bounds__(256) void k_quant5(const float* x, const float* wq,
                                                const float* wk, const float* wv,
                                                const float* wo) {
  int b = blockIdx.x;
  if      (b < 512)  quant_part(x,  g_Xq,  NS*NHID/4,   SL_X,  b,        512);
  else if (b < 1536) quant_part(wq, g_W1q, NHID*NHID/4, SL_WQ, b - 512,  1024);
  else if (b < 2048) quant_part(wk, g_Wkq, NKV*NHID/4,  SL_WK, b - 1536, 512);
  else if (b < 2560) quant_part(wv, g_Wvq, NKV*NHID/4,  SL_WV, b - 2048, 512);
  else               quant_part(wo, g_Woq, NHID*NHID/4, SL_WO, b - 2560, 1024);
}
__global__ __launch_bounds__(256) void k_quant8_oatt() {
  quant_part(g_qlin, g_Oq, NS*NHID/4, SL_OATT, blockIdx.x, 512);
}

// ---------- int8 GEMM with fused output absmax ----------
DEV void gemm_body(const int8_t* __restrict__ A, const int8_t* __restrict__ B,
                   const float* __restrict__ bias, float* __restrict__ C,
                   int N, int K, int sa, int sb, int outslot) {
  float scale = sc8(g_slots[sa]) * sc8(g_slots[sb]);
  int wave = threadIdx.x >> 6, lane = threadIdx.x & 63;
  int r = lane & 15, kg = lane >> 4;
  int m0 = blockIdx.y * 64 + wave * 16;
  int n0 = blockIdx.x * 64;
  const int8_t* ap = A + (m0 + r) * K + kg * 16;
  const int8_t* bp = B + (n0 + r) * K + kg * 16;
  v4i acc[4] = {{0,0,0,0},{0,0,0,0},{0,0,0,0},{0,0,0,0}};
  for (int kb = 0; kb < K; kb += 64) {
    v4i a = *(const v4i*)(ap + kb);
    #pragma unroll
    for (int j = 0; j < 4; j++) {
      v4i bf = *(const v4i*)(bp + j * 16 * K + kb);
      acc[j] = __builtin_amdgcn_mfma_i32_16x16x64_i8(a, bf, acc[j], 0, 0, 0);
    }
  }
  float am = 0.0f;
  #pragma unroll
  for (int j = 0; j < 4; j++) {
    int n = n0 + j * 16 + r;
    float bvf = bias ? bias[n] : 0.0f;
    #pragma unroll
    for (int t = 0; t < 4; t++) {
      int m = m0 + kg * 4 + t;
      float val = (float)acc[j][t] * scale + bvf;
      C[m * N + n] = val;
      am = fmaxf(am, fabsf(val));
    }
  }
  if (outslot >= 0) {
    am = block_reduce_max(am);
    if (threadIdx.x == 0) atomicMax((unsigned int*)&g_slots[outslot], __float_as_uint(am));
  }
}
__global__ __launch_bounds__(256) void k_gemm_q(const float* bias) {
  gemm_body(g_Xq, g_W1q, bias, g_qlin, NHID, NHID, SL_X, SL_WQ, SL_Q);
}
__global__ __launch_bounds__(256) void k_gemm_kv(const float* bias, float* C, int which) {
  gemm_body(g_Xq, which ? g_Wvq : g_Wkq, bias, C, NKV, NHID, SL_X,
            which ? SL_WV : SL_WK, which ? SL_VLIN : SL_K);
}
__global__ __launch_bounds__(256) void k_gemm_o(float* C) {
  gemm_body(g_Oq, g_Woq, nullptr, C, NHID, NHID, SL_OATT, SL_WO, -1);
}

// ---------- RoPE chain (fused q+k per stage) ----------
struct RS8 { float st, ist, st2, ist2, s2, is2, srh, isrh; };

DEV void rope_ab(const float* __restrict__ rowp, const float* __restrict__ cosp,
                 const float* __restrict__ sinp, int d4, const RS8& sc,
                 float* a, float* b) {
  float4 xv = *(const float4*)(rowp + d4);
  int pd = (d4 < 64) ? d4 + 64 : d4 - 64;
  float4 pv = *(const float4*)(rowp + pd);
  float4 cv = *(const float4*)(cosp + d4);
  float4 sv = *(const float4*)(sinp + d4);
  float xs[4] = {xv.x, xv.y, xv.z, xv.w};
  float ps[4] = {pv.x, pv.y, pv.z, pv.w};
  float cs[4] = {cv.x, cv.y, cv.z, cv.w};
  float ss[4] = {sv.x, sv.y, sv.z, sv.w};
  #pragma unroll
  for (int e = 0; e < 4; e++) {
    float v16 = fq_vali(xs[e], sc.st, sc.ist, 32767.f);
    float tp  = fq_vali(fq_vali(ps[e], sc.st, sc.ist, 32767.f), sc.st2, sc.ist2, 32767.f);
    float rh;
    if (d4 < 64) rh = fq_vali(fq_vali(-tp, sc.s2, sc.is2, 32767.f), sc.srh, sc.isrh, 32767.f);
    else         rh = fq_vali(tp, sc.srh, sc.isrh, 32767.f);
    a[e] = v16 * cs[e];
    b[e] = rh * ss[e];
  }
}

DEV RS8 mk_rsA(int slotT) {
  RS8 sc;
  sc.st = sc16(g_slots[slotT]);
  sc.ist = 1.0f / sc.st;
  sc.st2 = fmaxf(32767.f * sc.st, 1e-8f) / 32767.f;
  sc.ist2 = 1.0f / sc.st2;
  sc.s2 = 1.0f; sc.is2 = 1.0f; sc.srh = 1.0f; sc.isrh = 1.0f;
  return sc;
}
DEV RS8 mk_rs(int slotT, int slotH1, int slotH2) {
  RS8 sc;
  sc.st = sc16(g_slots[slotT]);
  sc.ist = 1.0f / sc.st;
  sc.st2 = fmaxf(32767.f * sc.st, 1e-8f) / 32767.f;
  sc.ist2 = 1.0f / sc.st2;
  sc.s2 = sc16(g_slots[slotH2]);
  sc.is2 = 1.0f / sc.s2;
  sc.srh = fmaxf(fmaxf(g_slots[slotH1], 32767.f * sc.s2), 1e-8f) / 32767.f;
  sc.isrh = 1.0f / sc.srh;
  return sc;
}

DEV void ropeA_part(const float* __restrict__ src, int nrows, const RS8& sc,
                    int sh1, int sh2, int b0, int nb) {
  int n4 = nrows * 32;
  float m1 = 0.f, m2 = 0.f;
  int stride = nb * 256;
  for (int i = b0 * 256 + threadIdx.x; i < n4; i += stride) {
    int d4 = (i & 31) << 2;
    int rowg = i >> 5;
    float4 xv = *(const float4*)(src + (rowg << 7) + d4);
    float xs[4] = {xv.x, xv.y, xv.z, xv.w};
    #pragma unroll
    for (int e = 0; e < 4; e++) {
      float t = fq_vali(fq_vali(xs[e], sc.st, sc.ist, 32767.f), sc.st2, sc.ist2, 32767.f);
      if (d4 < 64) m1 = fmaxf(m1, fabsf(t)); else m2 = fmaxf(m2, fabsf(t));
    }
  }
  m1 = block_reduce_max(m1);
  if (threadIdx.x == 0) atomicMax((unsigned int*)&g_slots[sh1], __float_as_uint(m1));
  m2 = block_reduce_max(m2);
  if (threadIdx.x == 0) atomicMax((unsigned int*)&g_slots[sh2], __float_as_uint(m2));
}

DEV void ropeBC_part(const float* __restrict__ src, const float* __restrict__ cosb,
                     const float* __restrict__ sinb, int nrows, int lgH, const RS8& sc,
                     int mode, float sa, float isa, float sb, float isb,
                     int o1, int o2, int b0, int nb) {
  int n4 = nrows * 32;
  float m1 = 0.f, m2 = 0.f;
  int stride = nb * 256;
  for (int i = b0 * 256 + threadIdx.x; i < n4; i += stride) {
    int d4 = (i & 31) << 2;
    int rowg = i >> 5;
    int s = rowg >> lgH;
    float a[4], b[4];
    rope_ab(src + (rowg << 7), cosb + (s << 7), sinb + (s << 7), d4, sc, a, b);
    if (mode == 0) {
      #pragma unroll
      for (int e = 0; e < 4; e++) { m1 = fmaxf(m1, fabsf(a[e])); m2 = fmaxf(m2, fabsf(b[e])); }
    } else {
      #pragma unroll
      for (int e = 0; e < 4; e++) {
        float ev = fq_vali(a[e], sa, isa, 32767.f) + fq_vali(b[e], sb, isb, 32767.f);
        m1 = fmaxf(m1, fabsf(ev));
      }
    }
  }
  m1 = block_reduce_max(m1);
  if (threadIdx.x == 0) atomicMax((unsigned int*)&g_slots[o1], __float_as_uint(m1));
  if (mode == 0) {
    m2 = block_reduce_max(m2);
    if (threadIdx.x == 0) atomicMax((unsigned int*)&g_slots[o2], __float_as_uint(m2));
  }
}

__global__ __launch_bounds__(256) void k_ropeA(const float* klin) {
  int b = blockIdx.x;
  if (b < 512) {
    RS8 sc = mk_rsA(SL_Q);
    ropeA_part(g_qlin, NHEAD * NS, sc, SL_QH1, SL_QH2, b, 512);
  } else {
    RS8 sc = mk_rsA(SL_K);
    ropeA_part(klin, NKVH * NS, sc, SL_KH1, SL_KH2, b - 512, 256);
  }
}
__global__ __launch_bounds__(256) void k_ropeB(const float* klin, const float* cosb, const float* sinb) {
  int b = blockIdx.x;
  if (b < 512) {
    RS8 sc = mk_rs(SL_Q, SL_QH1, SL_QH2);
    ropeBC_part(g_qlin, cosb, sinb, NHEAD * NS, 4, sc, 0, 0.f, 0.f, 0.f, 0.f, SL_QA, SL_QB, b, 512);
  } else {
    RS8 sc = mk_rs(SL_K, SL_KH1, SL_KH2);
    ropeBC_part(klin, cosb, sinb, NKVH * NS, 2, sc, 0, 0.f, 0.f, 0.f, 0.f, SL_KA, SL_KB, b - 512, 256);
  }
}
__global__ __launch_bounds__(256) void k_ropeC(const float* klin, const float* cosb, const float* sinb) {
  int b = blockIdx.x;
  if (b < 512) {
    RS8 sc = mk_rs(SL_Q, SL_QH1, SL_QH2);
    float sa = sc16(g_slots[SL_QA]), sb = sc16(g_slots[SL_QB]);
    ropeBC_part(g_qlin, cosb, sinb, NHEAD * NS, 4, sc, 1, sa, 1.0f/sa, sb, 1.0f/sb,
                SL_QEMB, 0, b, 512);
  } else {
    RS8 sc = mk_rs(SL_K, SL_KH1, SL_KH2);
    float sa = sc16(g_slots[SL_KA]), sb = sc16(g_slots[SL_KB]);
    ropeBC_part(klin, cosb, sinb, NKVH * NS, 2, sc, 1, sa, 1.0f/sa, sb, 1.0f/sb,
                SL_KEMB, 0, b - 512, 256);
  }
}

DEV void ropeD_part(const float* __restrict__ src, const float* __restrict__ cosb,
                    const float* __restrict__ sinb, int lgH, const RS8& sc,
                    float sa, float isa, float sb, float isb,
                    int isQ, float se, float ise, float isq, int b0) {
  int rowg = b0 * 8 + (threadIdx.x >> 5);
  int lane32 = threadIdx.x & 31;
  int d4 = lane32 << 2;
  int hmask = (1 << lgH) - 1;
  int h = rowg & hmask, s = rowg >> lgH;
  float a[4], b[4];
  rope_ab(src + (rowg << 7), cosb + (s << 7), sinb + (s << 7), d4, sc, a, b);
  if (isQ) {
    int rs = 0;
    signed char qb[4];
    #pragma unroll
    for (int e = 0; e < 4; e++) {
      float ev = fq_vali(a[e], sa, isa, 32767.f) + fq_vali(b[e], sb, isb, 32767.f);
      float e16 = fq_vali(ev, se, ise, 32767.f);
      float qf = fq_inti(e16, isq, 127.f);
      qb[e] = (signed char)(int)qf;
      rs += (int)qf;
    }
    *(char4*)(g_q8 + ((h << 10) + s) * ND + d4) = make_char4(qb[0], qb[1], qb[2], qb[3]);
    #pragma unroll
    for (int o = 16; o > 0; o >>= 1) rs += __shfl_down(rs, o, 32);
    if (lane32 == 0) g_rowsumQ[(h << 10) + s] = rs;
  } else {
    signed char qh[4], ql[4];
    #pragma unroll
    for (int e = 0; e < 4; e++) {
      float ev = fq_vali(a[e], sa, isa, 32767.f) + fq_vali(b[e], sb, isb, 32767.f);
      int q = (int)fq_inti(ev, isq, 32767.f);
      qh[e] = (signed char)(q >> 8);
      ql[e] = (signed char)((q & 255) - 128);
    }
    int off = (h * NC + 3072 + s) * ND + d4;
    *(char4*)(g_khi + off) = make_char4(qh[0], qh[1], qh[2], qh[3]);
    *(char4*)(g_klo + off) = make_char4(ql[0], ql[1], ql[2], ql[3]);
  }
}
__global__ __launch_bounds__(256) void k_ropeD(const float* klin, const float* cosb, const float* sinb) {
  int b = blockIdx.x;
  if (b < 2048) {
    RS8 sc = mk_rs(SL_Q, SL_QH1, SL_QH2);
    float sa = sc16(g_slots[SL_QA]), sb = sc16(g_slots[SL_QB]);
    float se = sc16(g_slots[SL_QEMB]);
    float s8 = fmaxf(32767.f * se, 1e-8f) / 127.f;
    ropeD_part(g_qlin, cosb, sinb, 4, sc, sa, 1.0f/sa, sb, 1.0f/sb,
               1, se, 1.0f/se, 1.0f/s8, b);
  } else {
    RS8 sc = mk_rs(SL_K, SL_KH1, SL_KH2);
    float sa = sc16(g_slots[SL_KA]), sb = sc16(g_slots[SL_KB]);
    float sck = fmaxf(fmaxf(g_slots[SL_KEMB], g_slots[SL_CKT]), 1e-8f) / 32767.f;
    ropeD_part(klin, cosb, sinb, 2, sc, sa, 1.0f/sa, sb, 1.0f/sb,
               0, 1.f, 1.f, 1.0f/sck, b - 2048);
  }
}

// ---------- ck tail quantize + cv transpose (+colsum) fused ----------
DEV void ck_tail_part(const float* __restrict__ cache_k, int b0, int nb) {
  float sck = fmaxf(fmaxf(g_slots[SL_KEMB], g_slots[SL_CKT]), 1e-8f) / 32767.f;
  float isck = 1.0f / sck;
  int n4 = NKVH * 3072 * 32;
  int stride = nb * 256;
  for (int i = b0 * 256 + threadIdx.x; i < n4; i += stride) {
    int d4 = (i & 31) << 2;
    int rc = i >> 5;
    int kvh = rc / 3072, rr = rc - kvh * 3072;
    float4 v = *(const float4*)(cache_k + kvh * (NC * ND) + (1024 + rr) * ND + d4);
    float xs[4] = {v.x, v.y, v.z, v.w};
    signed char qh[4], ql[4];
    #pragma unroll
    for (int e = 0; e < 4; e++) {
      int q = (int)fq_inti(xs[e], isck, 32767.f);
      qh[e] = (signed char)(q >> 8);
      ql[e] = (signed char)((q & 255) - 128);
    }
    int off = (kvh * NC + rr) * ND + d4;
    *(char4*)(g_khi + off) = make_char4(qh[0], qh[1], qh[2], qh[3]);
    *(char4*)(g_klo + off) = make_char4(ql[0], ql[1], ql[2], ql[3]);
  }
}
DEV void cvT_part(const float* __restrict__ cache_v, const float* __restrict__ vlin, int bb) {
  float scv = fmaxf(fmaxf(g_slots[SL_CVT], g_slots[SL_VLIN]), 1e-8f) / 127.f;
  float iscv = 1.0f / scv;
  int kvh = bb >> 7;
  int cblk = (bb >> 1) & 63;
  int dblk = bb & 1;
  int c0 = cblk * 64, d0 = dblk * 64;
  __shared__ int8_t tile[64][68];
  #pragma unroll 4
  for (int i = 0; i < 16; i++) {
    int cl = (threadIdx.x >> 6) * 16 + i;
    int dl = threadIdx.x & 63;
    int c = c0 + cl, d = d0 + dl;
    float v = (c < 3072) ? cache_v[kvh * (NC * ND) + (1024 + c) * ND + d]
                         : vlin[(c - 3072) * NKV + kvh * ND + d];
    tile[cl][dl] = (int8_t)(int)fq_inti(v, iscv, 127.f);
  }
  __syncthreads();
  #pragma unroll 4
  for (int i = 0; i < 16; i++) {
    int dl = (threadIdx.x >> 6) * 16 + i;
    int cl = threadIdx.x & 63;
    int8_t q = tile[cl][dl];
    g_vT[(kvh * ND + d0 + dl) * NC + c0 + cl] = q;
    int s = (int)q;
    #pragma unroll
    for (int o = 32; o > 0; o >>= 1) s += __shfl_down(s, o, 64);
    if (cl == 0) atomicAdd(&g_colsumV[kvh * ND + d0 + dl], s);
  }
}
__global__ __launch_bounds__(256) void k_ckcv(const float* cache_k, const float* cache_v,
                                              const float* vlin) {
  int b = blockIdx.x;
  if (b < 512) cvT_part(cache_v, vlin, b);
  else         ck_tail_part(cache_k, b - 512, 768);
}

// ---------- attention ----------
DEV float qk_smul() {
  float se = sc16(g_slots[SL_QEMB]);
  float s8 = fmaxf(32767.f * se, 1e-8f) / 127.f;
  float sck = fmaxf(fmaxf(g_slots[SL_KEMB], g_slots[SL_CKT]), 1e-8f) / 32767.f;
  return s8 * sck * 0.08838834764831845f;
}

// pass 1: K-in-regs (64-col chunks). block=(hg,chunk,rowq), 4 waves = 4 q-heads.
__global__ __launch_bounds__(256, 4) void k_attn1(const float* __restrict__ mask) {
  int b = blockIdx.x;
  int chunk = b & 63, rowq = (b >> 6) & 3, hg = b >> 8;
  int wave = threadIdx.x >> 6, lane = threadIdx.x & 63;
  int h = (hg << 2) + wave;
  int r = lane & 15, kg = lane >> 4;
  int kvbase = hg << 12;
  float smul = qk_smul();
  v4i B[4][4];
  #pragma unroll
  for (int j = 0; j < 4; j++) {
    int off = (kvbase + (chunk << 6) + (j << 4) + r) * ND + (kg << 4);
    B[j][0] = *(const v4i*)(g_khi + off);
    B[j][1] = *(const v4i*)(g_khi + off + 64);
    B[j][2] = *(const v4i*)(g_klo + off);
    B[j][3] = *(const v4i*)(g_klo + off + 64);
  }
  float amax = 0.f;
  int s0 = rowq << 8;
  for (int it = 0; it < 16; it++, s0 += 16) {
    const int8_t* qp = g_q8 + ((h << 10) + s0 + r) * ND + (kg << 4);
    v4i a0 = *(const v4i*)qp, a1 = *(const v4i*)(qp + 64);
    int rs[4];
    #pragma unroll
    for (int t = 0; t < 4; t++) rs[t] = g_rowsumQ[(h << 10) + s0 + (kg << 2) + t] << 7;
    const float* mrow = mask + (s0 + (kg << 2)) * NC + (chunk << 6) + r;
    float mx[4] = {-__builtin_inff(), -__builtin_inff(), -__builtin_inff(), -__builtin_inff()};
    #pragma unroll
    for (int j = 0; j < 4; j++) {
      v4i z = {0,0,0,0};
      v4i hi = __builtin_amdgcn_mfma_i32_16x16x64_i8(a0, B[j][0], z, 0, 0, 0);
      hi = __builtin_amdgcn_mfma_i32_16x16x64_i8(a1, B[j][1], hi, 0, 0, 0);
      v4i lo = __builtin_amdgcn_mfma_i32_16x16x64_i8(a0, B[j][2], z, 0, 0, 0);
      lo = __builtin_amdgcn_mfma_i32_16x16x64_i8(a1, B[j][3], lo, 0, 0, 0);
      #pragma unroll
      for (int t = 0; t < 4; t++) {
        int Li = (hi[t] << 8) + lo[t] + rs[t];
        float L = (float)Li * smul + mrow[t * NC + (j << 4)];
        mx[t] = fmaxf(mx[t], L);
        amax = fmaxf(amax, fabsf(L));
      }
    }
    #pragma unroll
    for (int o = 1; o <= 8; o <<= 1) {
      #pragma unroll
      for (int t = 0; t < 4; t++) mx[t] = fmaxf(mx[t], __shfl_xor(mx[t], o));
    }
    if (r == 0) {
      #pragma unroll
      for (int t = 0; t < 4; t++)
        g_LmaxP[chunk][(h << 10) + s0 + (kg << 2) + t] = mx[t];
    }
  }
  amax = block_reduce_max(amax);
  if (threadIdx.x == 0) atomicMax((unsigned int*)&g_slots[SL_LAM], __float_as_uint(amax));
}

// combine per-row max partials
__global__ __launch_bounds__(256) void k_rowmax() {
  int row = blockIdx.x * 256 + threadIdx.x;
  float m = -__builtin_inff();
  #pragma unroll 8
  for (int p = 0; p < 64; p++) m = fmaxf(m, g_LmaxP[p][row]);
  g_Lmax[row] = m;
}

// pass 2: K-in-regs, materialize int16 codes + per-chunk sum-exp partials
__global__ __launch_bounds__(256, 4) void k_attn2(const float* __restrict__ mask) {
  int b = blockIdx.x;
  int chunk = b & 63, rowq = (b >> 6) & 3, hg = b >> 8;
  int wave = threadIdx.x >> 6, lane = threadIdx.x & 63;
  int h = (hg << 2) + wave;
  int r = lane & 15, kg = lane >> 4;
  int kvbase = hg << 12;
  float smul = qk_smul();
  float sL = sc16(g_slots[SL_LAM]);
  float invsL = 1.0f / sL;
  v4i B[4][4];
  #pragma unroll
  for (int j = 0; j < 4; j++) {
    int off = (kvbase + (chunk << 6) + (j << 4) + r) * ND + (kg << 4);
    B[j][0] = *(const v4i*)(g_khi + off);
    B[j][1] = *(const v4i*)(g_khi + off + 64);
    B[j][2] = *(const v4i*)(g_klo + off);
    B[j][3] = *(const v4i*)(g_klo + off + 64);
  }
  int s0 = rowq << 8;
  for (int it = 0; it < 16; it++, s0 += 16) {
    const int8_t* qp = g_q8 + ((h << 10) + s0 + r) * ND + (kg << 4);
    v4i a0 = *(const v4i*)qp, a1 = *(const v4i*)(qp + 64);
    int rs[4];
    float mc[4];
    #pragma unroll
    for (int t = 0; t < 4; t++) {
      int row = (h << 10) + s0 + (kg << 2) + t;
      rs[t] = g_rowsumQ[row] << 7;
      mc[t] = fminf(fmaxf(rintf(g_Lmax[row] * invsL), -32768.f), 32767.f);
    }
    const float* mrow = mask + (s0 + (kg << 2)) * NC + (chunk << 6) + r;
    unsigned short* pbase = g_L16 + (((h << 6) + chunk) << 16) + ((s0 + (kg << 2)) << 6) + r;
    float sm[4] = {0.f, 0.f, 0.f, 0.f};
    #pragma unroll
    for (int j = 0; j < 4; j++) {
      v4i z = {0,0,0,0};
      v4i hi = __builtin_amdgcn_mfma_i32_16x16x64_i8(a0, B[j][0], z, 0, 0, 0);
      hi = __builtin_amdgcn_mfma_i32_16x16x64_i8(a1, B[j][1], hi, 0, 0, 0);
      v4i lo = __builtin_amdgcn_mfma_i32_16x16x64_i8(a0, B[j][2], z, 0, 0, 0);
      lo = __builtin_amdgcn_mfma_i32_16x16x64_i8(a1, B[j][3], lo, 0, 0, 0);
      #pragma unroll
      for (int t = 0; t < 4; t++) {
        int Li = (hi[t] << 8) + lo[t] + rs[t];
        float L = (float)Li * smul + mrow[t * NC + (j << 4)];
        float cf = rintf(L * invsL);
        pbase[(t << 6) + (j << 4)] = (unsigned short)(int)cf;
        sm[t] += __expf((cf - mc[t]) * sL);
      }
    }
    #pragma unroll
    for (int o = 1; o <= 8; o <<= 1) {
      #pragma unroll
      for (int t = 0; t < 4; t++) sm[t] += __shfl_xor(sm[t], o);
    }
    if (r == 0) {
      #pragma unroll
      for (int t = 0; t < 4; t++)
        g_LsP[chunk][(h << 10) + s0 + (kg << 2) + t] = sm[t];
    }
  }
}

// combine row sums (fixed order) + global min-sum
__global__ __launch_bounds__(256) void k_minsum() {
  int row = blockIdx.x * 256 + threadIdx.x;
  float sr = 0.f;
  #pragma unroll 8
  for (int p = 0; p < 64; p++) sr += g_LsP[p][row];
  g_Lsum[row] = sr;
  float m = sr;
  #pragma unroll
  for (int o = 32; o > 0; o >>= 1) m = fminf(m, __shfl_down(m, o, 64));
  __shared__ float red[4];
  __syncthreads();
  if ((threadIdx.x & 63) == 0) red[threadIdx.x >> 6] = m;
  __syncthreads();
  if (threadIdx.x == 0) {
    float v = fminf(fminf(red[0], red[1]), fminf(red[2], red[3]));
    atomicMin((unsigned int*)&g_slots[SL_MINSUM], __float_as_uint(v));
  }
}

// pass 3: P from codes -> PV (int MFMA), fused output absmax.
// Structural plateau: 64 AGPR acc + ~60 VGPR -> 4 waves/SIMD hard cap;
// r6 prefetch, r8 (256,8) coercion, r9 cb-split all measured <= this form.
__global__ __launch_bounds__(256, 4) void k_attn3() {
  int h = blockIdx.x >> 6;
  int s0 = (blockIdx.x & 63) << 4;
  int wave = threadIdx.x >> 6, lane = threadIdx.x & 63;
  int r = lane & 15, kg = lane >> 4;
  int kvh = h >> 2;
  float sL = sc16(g_slots[SL_LAM]);
  float invsL = 1.0f / sL;
  float sP = fmaxf(1.0f / g_slots[SL_MINSUM], 1e-8f) / 32767.f;
  float invsP = 1.0f / sP;
  float sV = fmaxf(fmaxf(g_slots[SL_CVT], g_slots[SL_VLIN]), 1e-8f) / 127.f;
  int arow = (h << 10) + s0 + r;
  float mrc = fminf(fmaxf(rintf(g_Lmax[arow] * invsL), -32768.f), 32767.f);
  float rowscale = (1.0f / g_Lsum[arow]) * invsP;
  float Crow = __logf(rowscale) - mrc * sL;
  v4i accH[8], accL[8];
  #pragma unroll
  for (int j = 0; j < 8; j++) { accH[j] = (v4i){0,0,0,0}; accL[j] = (v4i){0,0,0,0}; }
  for (int cb = wave; cb < 64; cb += 4) {
    const unsigned short* cp = g_L16 + (((h << 6) + cb) << 16) + ((s0 + r) << 6) + kg * 16;
    v8s cA = *(const v8s*)cp;
    v8s cB = *(const v8s*)(cp + 8);
    int pq[16];
    #pragma unroll
    for (int j = 0; j < 8; j++) {
      float p = __expf((float)cA[j] * sL + Crow);
      pq[j] = (int)fminf(rintf(p), 32767.f);
    }
    #pragma unroll
    for (int j = 0; j < 8; j++) {
      float p = __expf((float)cB[j] * sL + Crow);
      pq[8 + j] = (int)fminf(rintf(p), 32767.f);
    }
    int hw[4], lw[4];
    #pragma unroll
    for (int w = 0; w < 4; w++) {
      hw[w] = (pq[4*w] >> 8) | ((pq[4*w+1] >> 8) << 8) | ((pq[4*w+2] >> 8) << 16) | ((pq[4*w+3] >> 8) << 24);
      lw[w] = ((pq[4*w] & 255) ^ 128) | (((pq[4*w+1] & 255) ^ 128) << 8)
            | (((pq[4*w+2] & 255) ^ 128) << 16) | (((pq[4*w+3] & 255) ^ 128) << 24);
    }
    v4i paH = {hw[0], hw[1], hw[2], hw[3]};
    v4i paL = {lw[0], lw[1], lw[2], lw[3]};
    #pragma unroll
    for (int j = 0; j < 8; j++) {
      v4i bv = *(const v4i*)(g_vT + (kvh * ND + j * 16 + r) * NC + cb * 64 + kg * 16);
      accH[j] = __builtin_amdgcn_mfma_i32_16x16x64_i8(paH, bv, accH[j], 0, 0, 0);
      accL[j] = __builtin_amdgcn_mfma_i32_16x16x64_i8(paL, bv, accL[j], 0, 0, 0);
    }
  }
  __shared__ int bufH[16][132];
  __shared__ int bufL[16][132];
  for (int e = threadIdx.x; e < 2048; e += 256) {
    bufH[e >> 7][e & 127] = 0;
    bufL[e >> 7][e & 127] = 0;
  }
  __syncthreads();
  #pragma unroll
  for (int j = 0; j < 8; j++) {
    #pragma unroll
    for (int t = 0; t < 4; t++) {
      atomicAdd(&bufH[kg * 4 + t][j * 16 + r], accH[j][t]);
      atomicAdd(&bufL[kg * 4 + t][j * 16 + r], accL[j][t]);
    }
  }
  __syncthreads();
  double scale = (double)sP * (double)sV;
  float am = 0.f;
  for (int e = threadIdx.x; e < 2048; e += 256) {
    int s = e >> 7, d = e & 127;
    double tot = 256.0 * (double)bufH[s][d] + (double)bufL[s][d]
               + 128.0 * (double)g_colsumV[kvh * ND + d];
    float val = (float)(tot * scale);
    g_qlin[((s0 + s) << 11) + (h << 7) + d] = val;
    am = fmaxf(am, fabsf(val));
  }
  am = block_reduce_max(am);
  if (threadIdx.x == 0) atomicMax((unsigned int*)&g_slots[SL_OATT], __float_as_uint(am));
}

extern "C" void kernel_launch(void* const* d_in, const int* in_sizes, int n_in,
                              void* d_out, int out_size, void* d_ws, size_t ws_size,
                              hipStream_t stream) {
  (void)in_sizes; (void)n_in; (void)out_size; (void)d_ws; (void)ws_size;
  const float* x      = (const float*)d_in[0];
  const float* cosb   = (const float*)d_in[1];
  const float* sinb   = (const float*)d_in[2];
  const float* cachek = (const float*)d_in[3];
  const float* cachev = (const float*)d_in[4];
  const float* mask   = (const float*)d_in[5];
  const float* Wq     = (const float*)d_in[6];
  const float* bq     = (const float*)d_in[7];
  const float* Wk     = (const float*)d_in[8];
  const float* bk     = (const float*)d_in[9];
  const float* Wv     = (const float*)d_in[10];
  const float* bv     = (const float*)d_in[11];
  const float* Wo     = (const float*)d_in[12];
  float* outO = (float*)d_out;
  float* outK = outO + NS * NHID;
  float* outV = outK + NS * NKV;

  k_init<<<1, 256, 0, stream>>>();
  k_absmax7<<<4608, 256, 0, stream>>>(x, Wq, Wk, Wv, Wo, cachek, cachev);
  k_quant5<<<3584, 256, 0, stream>>>(x, Wq, Wk, Wv, Wo);
  k_gemm_q<<<dim3(NHID / 64, NS / 64), 256, 0, stream>>>(bq);
  k_gemm_kv<<<dim3(NKV / 64, NS / 64), 256, 0, stream>>>(bk, outK, 0);
  k_gemm_kv<<<dim3(NKV / 64, NS / 64), 256, 0, stream>>>(bv, outV, 1);
  k_ropeA<<<768, 256, 0, stream>>>(outK);
  k_ropeB<<<768, 256, 0, stream>>>(outK, cosb, sinb);
  k_ropeC<<<768, 256, 0, stream>>>(outK, cosb, sinb);
  k_ropeD<<<2560, 256, 0, stream>>>(outK, cosb, sinb);
  k_ckcv<<<1280, 256, 0, stream>>>(cachek, cachev, outV);
  k_attn1<<<1024, 256, 0, stream>>>(mask);
  k_rowmax<<<64, 256, 0, stream>>>();
  k_attn2<<<1024, 256, 0, stream>>>(mask);
  k_minsum<<<64, 256, 0, stream>>>();
  k_attn3<<<1024, 256, 0, stream>>>();
  k_quant8_oatt<<<512, 256, 0, stream>>>();
  k_gemm_o<<<dim3(NHID / 64, NS / 64), 256, 0, stream>>>(outO);
}

// Round 12
// 460.631 us; speedup vs baseline: 1.1743x; 1.0408x over previous
//
#include <hip/hip_runtime.h>
#include <stdint.h>

typedef int v4i __attribute__((ext_vector_type(4)));
typedef short v8s __attribute__((ext_vector_type(8)));
#define DEV __device__ __forceinline__

constexpr int NS    = 1024;
constexpr int NHID  = 2048;
constexpr int NHEAD = 16;
constexpr int NKVH  = 4;
constexpr int ND    = 128;
constexpr int NC    = 4096;
constexpr int NKV   = 512;

#define SL_X 0
#define SL_WQ 1
#define SL_WK 2
#define SL_WV 3
#define SL_WO 4
#define SL_Q 5
#define SL_K 6
#define SL_QH1 7
#define SL_QH2 8
#define SL_KH1 9
#define SL_KH2 10
#define SL_QA 11
#define SL_QB 12
#define SL_KA 13
#define SL_KB 14
#define SL_QEMB 15
#define SL_KEMB 16
#define SL_CKT 17
#define SL_CVT 18
#define SL_VLIN 19
#define SL_LAM 20
#define SL_MINSUM 21
#define SL_OATT 22
// raw half-maxes of gemm outputs (d<64 / d>=64 per 128-col head), captured in
// GEMM epilogues; ropeA deleted via max|fq(fq(x))| = fq(fq(max|x|)) identity
#define SL_QM1 23
#define SL_KM1 25

__device__ float g_slots[64];
__device__ int   g_rowsumQ[NHEAD * NS];
__device__ float g_LmaxP[64][NHEAD * NS];
__device__ float g_LsP[64][NHEAD * NS];
__device__ float g_Lmax[NHEAD * NS];
__device__ float g_Lsum[NHEAD * NS];
__device__ int   g_colsumV[NKVH * ND];
__device__ __align__(16) int8_t g_Xq[NS * NHID];
__device__ __align__(16) int8_t g_W1q[NHID * NHID];
__device__ __align__(16) int8_t g_Woq[NHID * NHID];
__device__ __align__(16) int8_t g_Wkq[NKV * NHID];
__device__ __align__(16) int8_t g_Wvq[NKV * NHID];
__device__ __align__(16) float  g_qlin[NS * NHID];
__device__ __align__(16) int8_t g_q8[NHEAD * NS * ND];
__device__ __align__(16) int8_t g_khi[NKVH * NC * ND];
__device__ __align__(16) int8_t g_klo[NKVH * NC * ND];
__device__ __align__(16) int8_t g_vT[NKVH * ND * NC];
__device__ __align__(16) int8_t g_Oq[NS * NHID];
// int16 logit codes, tiled [h][cb=64][s=1024][64 cols] — 64-col chunks keep
// every 128B store line owned by one block (32-col chunks caused 1.7x write
// amplification, R10)
__device__ __align__(16) unsigned short g_L16[NHEAD * 64 * NS * 64];

DEV float sc8(float a)  { return fmaxf(a, 1e-8f) / 127.0f; }
DEV float sc16(float a) { return fmaxf(a, 1e-8f) / 32767.0f; }

DEV float fq_vali(float x, float s, float invs, float qmax) {
  float q = rintf(x * invs);
  q = fminf(fmaxf(q, -qmax - 1.0f), qmax);
  return q * s;
}
DEV float fq_inti(float x, float invs, float qmax) {
  float q = rintf(x * invs);
  return fminf(fmaxf(q, -qmax - 1.0f), qmax);
}

DEV float block_reduce_max(float m) {
  #pragma unroll
  for (int o = 32; o > 0; o >>= 1) m = fmaxf(m, __shfl_down(m, o, 64));
  __shared__ float red[4];
  __syncthreads();
  if ((threadIdx.x & 63) == 0) red[threadIdx.x >> 6] = m;
  __syncthreads();
  return fmaxf(fmaxf(red[0], red[1]), fmaxf(red[2], red[3]));
}

__global__ void k_init() {
  int t = threadIdx.x;
  if (t < 64) g_slots[t] = (t == SL_MINSUM) ? __builtin_inff() : 0.0f;
  g_colsumV[t] = 0;
  g_colsumV[t + 256] = 0;
}

// ---------- fused absmax over 5 raw inputs + cache tails ----------
DEV void absmax_part(const float* __restrict__ in, int n4, int slot, int b0, int nb) {
  float m = 0.0f;
  int stride = nb * 256;
  for (int i = b0 * 256 + threadIdx.x; i < n4; i += stride) {
    float4 v = ((const float4*)in)[i];
    m = fmaxf(m, fmaxf(fmaxf(fabsf(v.x), fabsf(v.y)), fmaxf(fabsf(v.z), fabsf(v.w))));
  }
  m = block_reduce_max(m);
  if (threadIdx.x == 0) atomicMax((unsigned int*)&g_slots[slot], __float_as_uint(m));
}
DEV void absmax_cache_part(const float* __restrict__ src, int slot, int b0, int nb) {
  float m = 0.0f;
  int stride = nb * 256;
  const int n4 = NKVH * 3072 * 32;
  for (int i = b0 * 256 + threadIdx.x; i < n4; i += stride) {
    int d4 = (i & 31) << 2;
    int rc = i >> 5;
    int kvh = rc / 3072, rr = rc - kvh * 3072;
    float4 v = *(const float4*)(src + kvh * (NC * ND) + (1024 + rr) * ND + d4);
    m = fmaxf(m, fmaxf(fmaxf(fabsf(v.x), fabsf(v.y)), fmaxf(fabsf(v.z), fabsf(v.w))));
  }
  m = block_reduce_max(m);
  if (threadIdx.x == 0) atomicMax((unsigned int*)&g_slots[slot], __float_as_uint(m));
}
__global__ __launch_bounds__(256) void k_absmax7(const float* x, const float* wq,
                                                 const float* wk, const float* wv,
                                                 const float* wo, const float* ck,
                                                 const float* cv) {
  int b = blockIdx.x;
  if      (b < 512)  absmax_part(x,  NS*NHID/4,   SL_X,  b,        512);
  else if (b < 1536) absmax_part(wq, NHID*NHID/4, SL_WQ, b - 512,  1024);
  else if (b < 2048) absmax_part(wk, NKV*NHID/4,  SL_WK, b - 1536, 512);
  else if (b < 2560) absmax_part(wv, NKV*NHID/4,  SL_WV, b - 2048, 512);
  else if (b < 3584) absmax_part(wo, NHID*NHID/4, SL_WO, b - 2560, 1024);
  else if (b < 4096) absmax_cache_part(ck, SL_CKT, b - 3584, 512);
  else               absmax_cache_part(cv, SL_CVT, b - 4096, 512);
}

// ---------- fused quantize of x + 4 weights ----------
DEV void quant_part(const float* __restrict__ in, int8_t* __restrict__ out,
                    int n4, int slot, int b0, int nb) {
  float s = sc8(g_slots[slot]);
  float is = 1.0f / s;
  int stride = nb * 256;
  for (int i = b0 * 256 + threadIdx.x; i < n4; i += stride) {
    float4 v = ((const float4*)in)[i];
    char4 q = make_char4((signed char)(int)fq_inti(v.x, is, 127.f),
                         (signed char)(int)fq_inti(v.y, is, 127.f),
                         (signed char)(int)fq_inti(v.z, is, 127.f),
                         (signed char)(int)fq_inti(v.w, is, 127.f));
    ((char4*)out)[i] = q;
  }
}
__global__ __launch_bounds__(256) void k_quant5(const float* x, const float* wq,
                                                const float* wk, const float* wv,
                                                const float* wo) {
  int b = blockIdx.x;
  if      (b < 512)  quant_part(x,  g_Xq,  NS*NHID/4,   SL_X,  b,        512);
  else if (b < 1536) quant_part(wq, g_W1q, NHID*NHID/4, SL_WQ, b - 512,  1024);
  else if (b < 2048) quant_part(wk, g_Wkq, NKV*NHID/4,  SL_WK, b - 1536, 512);
  else if (b < 2560) quant_part(wv, g_Wvq, NKV*NHID/4,  SL_WV, b - 2048, 512);
  else               quant_part(wo, g_Woq, NHID*NHID/4, SL_WO, b - 2560, 1024);
}
__global__ __launch_bounds__(256) void k_quant8_oatt() {
  quant_part(g_qlin, g_Oq, NS*NHID/4, SL_OATT, blockIdx.x, 512);
}

// ---------- int8 GEMM with fused output absmax (+ optional half-column max) ----------
DEV void gemm_body(const int8_t* __restrict__ A, const int8_t* __restrict__ B,
                   const float* __restrict__ bias, float* __restrict__ C,
                   int N, int K, int sa, int sb, int outslot, int halfslot) {
  float scale = sc8(g_slots[sa]) * sc8(g_slots[sb]);
  int wave = threadIdx.x >> 6, lane = threadIdx.x & 63;
  int r = lane & 15, kg = lane >> 4;
  int m0 = blockIdx.y * 64 + wave * 16;
  int n0 = blockIdx.x * 64;
  const int8_t* ap = A + (m0 + r) * K + kg * 16;
  const int8_t* bp = B + (n0 + r) * K + kg * 16;
  v4i acc[4] = {{0,0,0,0},{0,0,0,0},{0,0,0,0},{0,0,0,0}};
  for (int kb = 0; kb < K; kb += 64) {
    v4i a = *(const v4i*)(ap + kb);
    #pragma unroll
    for (int j = 0; j < 4; j++) {
      v4i bf = *(const v4i*)(bp + j * 16 * K + kb);
      acc[j] = __builtin_amdgcn_mfma_i32_16x16x64_i8(a, bf, acc[j], 0, 0, 0);
    }
  }
  float am = 0.0f;
  #pragma unroll
  for (int j = 0; j < 4; j++) {
    int n = n0 + j * 16 + r;
    float bvf = bias ? bias[n] : 0.0f;
    #pragma unroll
    for (int t = 0; t < 4; t++) {
      int m = m0 + kg * 4 + t;
      float val = (float)acc[j][t] * scale + bvf;
      C[m * N + n] = val;
      am = fmaxf(am, fabsf(val));
    }
  }
  if (outslot >= 0) {
    am = block_reduce_max(am);
    if (threadIdx.x == 0) {
      atomicMax((unsigned int*)&g_slots[outslot], __float_as_uint(am));
      // this block's 64 columns lie entirely in one 64-half of a 128-col head
      if (halfslot >= 0)
        atomicMax((unsigned int*)&g_slots[halfslot + ((n0 >> 6) & 1)], __float_as_uint(am));
    }
  }
}
__global__ __launch_bounds__(256) void k_gemm_q(const float* bias) {
  gemm_body(g_Xq, g_W1q, bias, g_qlin, NHID, NHID, SL_X, SL_WQ, SL_Q, SL_QM1);
}
__global__ __launch_bounds__(256) void k_gemm_kv(const float* bias, float* C, int which) {
  gemm_body(g_Xq, which ? g_Wvq : g_Wkq, bias, C, NKV, NHID, SL_X,
            which ? SL_WV : SL_WK, which ? SL_VLIN : SL_K, which ? -1 : SL_KM1);
}
__global__ __launch_bounds__(256) void k_gemm_o(float* C) {
  gemm_body(g_Oq, g_Woq, nullptr, C, NHID, NHID, SL_OATT, SL_WO, -1, -1);
}

// ---------- RoPE chain (ropeA deleted: m1/m2 derived from raw half-maxes) ----------
struct RS8 { float st, ist, st2, ist2, s2, is2, srh, isrh; };

DEV void rope_ab(const float* __restrict__ rowp, const float* __restrict__ cosp,
                 const float* __restrict__ sinp, int d4, const RS8& sc,
                 float* a, float* b) {
  float4 xv = *(const float4*)(rowp + d4);
  int pd = (d4 < 64) ? d4 + 64 : d4 - 64;
  float4 pv = *(const float4*)(rowp + pd);
  float4 cv = *(const float4*)(cosp + d4);
  float4 sv = *(const float4*)(sinp + d4);
  float xs[4] = {xv.x, xv.y, xv.z, xv.w};
  float ps[4] = {pv.x, pv.y, pv.z, pv.w};
  float cs[4] = {cv.x, cv.y, cv.z, cv.w};
  float ss[4] = {sv.x, sv.y, sv.z, sv.w};
  #pragma unroll
  for (int e = 0; e < 4; e++) {
    float v16 = fq_vali(xs[e], sc.st, sc.ist, 32767.f);
    float tp  = fq_vali(fq_vali(ps[e], sc.st, sc.ist, 32767.f), sc.st2, sc.ist2, 32767.f);
    float rh;
    if (d4 < 64) rh = fq_vali(fq_vali(-tp, sc.s2, sc.is2, 32767.f), sc.srh, sc.isrh, 32767.f);
    else         rh = fq_vali(tp, sc.srh, sc.isrh, 32767.f);
    a[e] = v16 * cs[e];
    b[e] = rh * ss[e];
  }
}

// m_half = max|fq(fq(x, st), st2)| over a half = fq(fq(max|x|)) — fq∘fq is
// monotone and odd (rint half-even symmetric; clamps inactive since
// |x| <= absmax = 32767*st), so the identity is exact.
DEV RS8 mk_rs(int slotT, int slotM1) {
  RS8 sc;
  sc.st = sc16(g_slots[slotT]);
  sc.ist = 1.0f / sc.st;
  sc.st2 = fmaxf(32767.f * sc.st, 1e-8f) / 32767.f;
  sc.ist2 = 1.0f / sc.st2;
  float m1 = fq_vali(fq_vali(g_slots[slotM1],     sc.st, sc.ist, 32767.f), sc.st2, sc.ist2, 32767.f);
  float m2 = fq_vali(fq_vali(g_slots[slotM1 + 1], sc.st, sc.ist, 32767.f), sc.st2, sc.ist2, 32767.f);
  sc.s2 = sc16(m2);
  sc.is2 = 1.0f / sc.s2;
  sc.srh = fmaxf(fmaxf(m1, 32767.f * sc.s2), 1e-8f) / 32767.f;
  sc.isrh = 1.0f / sc.srh;
  return sc;
}

DEV void ropeBC_part(const float* __restrict__ src, const float* __restrict__ cosb,
                     const float* __restrict__ sinb, int nrows, int lgH, const RS8& sc,
                     int mode, float sa, float isa, float sb, float isb,
                     int o1, int o2, int b0, int nb) {
  int n4 = nrows * 32;
  float m1 = 0.f, m2 = 0.f;
  int stride = nb * 256;
  for (int i = b0 * 256 + threadIdx.x; i < n4; i += stride) {
    int d4 = (i & 31) << 2;
    int rowg = i >> 5;
    int s = rowg >> lgH;
    float a[4], b[4];
    rope_ab(src + (rowg << 7), cosb + (s << 7), sinb + (s << 7), d4, sc, a, b);
    if (mode == 0) {
      #pragma unroll
      for (int e = 0; e < 4; e++) { m1 = fmaxf(m1, fabsf(a[e])); m2 = fmaxf(m2, fabsf(b[e])); }
    } else {
      #pragma unroll
      for (int e = 0; e < 4; e++) {
        float ev = fq_vali(a[e], sa, isa, 32767.f) + fq_vali(b[e], sb, isb, 32767.f);
        m1 = fmaxf(m1, fabsf(ev));
      }
    }
  }
  m1 = block_reduce_max(m1);
  if (threadIdx.x == 0) atomicMax((unsigned int*)&g_slots[o1], __float_as_uint(m1));
  if (mode == 0) {
    m2 = block_reduce_max(m2);
    if (threadIdx.x == 0) atomicMax((unsigned int*)&g_slots[o2], __float_as_uint(m2));
  }
}

__global__ __launch_bounds__(256) void k_ropeB(const float* klin, const float* cosb, const float* sinb) {
  int b = blockIdx.x;
  if (b < 512) {
    RS8 sc = mk_rs(SL_Q, SL_QM1);
    ropeBC_part(g_qlin, cosb, sinb, NHEAD * NS, 4, sc, 0, 0.f, 0.f, 0.f, 0.f, SL_QA, SL_QB, b, 512);
  } else {
    RS8 sc = mk_rs(SL_K, SL_KM1);
    ropeBC_part(klin, cosb, sinb, NKVH * NS, 2, sc, 0, 0.f, 0.f, 0.f, 0.f, SL_KA, SL_KB, b - 512, 256);
  }
}
__global__ __launch_bounds__(256) void k_ropeC(const float* klin, const float* cosb, const float* sinb) {
  int b = blockIdx.x;
  if (b < 512) {
    RS8 sc = mk_rs(SL_Q, SL_QM1);
    float sa = sc16(g_slots[SL_QA]), sb = sc16(g_slots[SL_QB]);
    ropeBC_part(g_qlin, cosb, sinb, NHEAD * NS, 4, sc, 1, sa, 1.0f/sa, sb, 1.0f/sb,
                SL_QEMB, 0, b, 512);
  } else {
    RS8 sc = mk_rs(SL_K, SL_KM1);
    float sa = sc16(g_slots[SL_KA]), sb = sc16(g_slots[SL_KB]);
    ropeBC_part(klin, cosb, sinb, NKVH * NS, 2, sc, 1, sa, 1.0f/sa, sb, 1.0f/sb,
                SL_KEMB, 0, b - 512, 256);
  }
}

DEV void ropeD_part(const float* __restrict__ src, const float* __restrict__ cosb,
                    const float* __restrict__ sinb, int lgH, const RS8& sc,
                    float sa, float isa, float sb, float isb,
                    int isQ, float se, float ise, float isq, int b0) {
  int rowg = b0 * 8 + (threadIdx.x >> 5);
  int lane32 = threadIdx.x & 31;
  int d4 = lane32 << 2;
  int hmask = (1 << lgH) - 1;
  int h = rowg & hmask, s = rowg >> lgH;
  float a[4], b[4];
  rope_ab(src + (rowg << 7), cosb + (s << 7), sinb + (s << 7), d4, sc, a, b);
  if (isQ) {
    int rs = 0;
    signed char qb[4];
    #pragma unroll
    for (int e = 0; e < 4; e++) {
      float ev = fq_vali(a[e], sa, isa, 32767.f) + fq_vali(b[e], sb, isb, 32767.f);
      float e16 = fq_vali(ev, se, ise, 32767.f);
      float qf = fq_inti(e16, isq, 127.f);
      qb[e] = (signed char)(int)qf;
      rs += (int)qf;
    }
    *(char4*)(g_q8 + ((h << 10) + s) * ND + d4) = make_char4(qb[0], qb[1], qb[2], qb[3]);
    #pragma unroll
    for (int o = 16; o > 0; o >>= 1) rs += __shfl_down(rs, o, 32);
    if (lane32 == 0) g_rowsumQ[(h << 10) + s] = rs;
  } else {
    signed char qh[4], ql[4];
    #pragma unroll
    for (int e = 0; e < 4; e++) {
      float ev = fq_vali(a[e], sa, isa, 32767.f) + fq_vali(b[e], sb, isb, 32767.f);
      int q = (int)fq_inti(ev, isq, 32767.f);
      qh[e] = (signed char)(q >> 8);
      ql[e] = (signed char)((q & 255) - 128);
    }
    int off = (h * NC + 3072 + s) * ND + d4;
    *(char4*)(g_khi + off) = make_char4(qh[0], qh[1], qh[2], qh[3]);
    *(char4*)(g_klo + off) = make_char4(ql[0], ql[1], ql[2], ql[3]);
  }
}
__global__ __launch_bounds__(256) void k_ropeD(const float* klin, const float* cosb, const float* sinb) {
  int b = blockIdx.x;
  if (b < 2048) {
    RS8 sc = mk_rs(SL_Q, SL_QM1);
    float sa = sc16(g_slots[SL_QA]), sb = sc16(g_slots[SL_QB]);
    float se = sc16(g_slots[SL_QEMB]);
    float s8 = fmaxf(32767.f * se, 1e-8f) / 127.f;
    ropeD_part(g_qlin, cosb, sinb, 4, sc, sa, 1.0f/sa, sb, 1.0f/sb,
               1, se, 1.0f/se, 1.0f/s8, b);
  } else {
    RS8 sc = mk_rs(SL_K, SL_KM1);
    float sa = sc16(g_slots[SL_KA]), sb = sc16(g_slots[SL_KB]);
    float sck = fmaxf(fmaxf(g_slots[SL_KEMB], g_slots[SL_CKT]), 1e-8f) / 32767.f;
    ropeD_part(klin, cosb, sinb, 2, sc, sa, 1.0f/sa, sb, 1.0f/sb,
               0, 1.f, 1.f, 1.0f/sck, b - 2048);
  }
}

// ---------- ck tail quantize + cv transpose (+colsum) fused ----------
DEV void ck_tail_part(const float* __restrict__ cache_k, int b0, int nb) {
  float sck = fmaxf(fmaxf(g_slots[SL_KEMB], g_slots[SL_CKT]), 1e-8f) / 32767.f;
  float isck = 1.0f / sck;
  int n4 = NKVH * 3072 * 32;
  int stride = nb * 256;
  for (int i = b0 * 256 + threadIdx.x; i < n4; i += stride) {
    int d4 = (i & 31) << 2;
    int rc = i >> 5;
    int kvh = rc / 3072, rr = rc - kvh * 3072;
    float4 v = *(const float4*)(cache_k + kvh * (NC * ND) + (1024 + rr) * ND + d4);
    float xs[4] = {v.x, v.y, v.z, v.w};
    signed char qh[4], ql[4];
    #pragma unroll
    for (int e = 0; e < 4; e++) {
      int q = (int)fq_inti(xs[e], isck, 32767.f);
      qh[e] = (signed char)(q >> 8);
      ql[e] = (signed char)((q & 255) - 128);
    }
    int off = (kvh * NC + rr) * ND + d4;
    *(char4*)(g_khi + off) = make_char4(qh[0], qh[1], qh[2], qh[3]);
    *(char4*)(g_klo + off) = make_char4(ql[0], ql[1], ql[2], ql[3]);
  }
}
DEV void cvT_part(const float* __restrict__ cache_v, const float* __restrict__ vlin, int bb) {
  float scv = fmaxf(fmaxf(g_slots[SL_CVT], g_slots[SL_VLIN]), 1e-8f) / 127.f;
  float iscv = 1.0f / scv;
  int kvh = bb >> 7;
  int cblk = (bb >> 1) & 63;
  int dblk = bb & 1;
  int c0 = cblk * 64, d0 = dblk * 64;
  __shared__ int8_t tile[64][68];
  #pragma unroll 4
  for (int i = 0; i < 16; i++) {
    int cl = (threadIdx.x >> 6) * 16 + i;
    int dl = threadIdx.x & 63;
    int c = c0 + cl, d = d0 + dl;
    float v = (c < 3072) ? cache_v[kvh * (NC * ND) + (1024 + c) * ND + d]
                         : vlin[(c - 3072) * NKV + kvh * ND + d];
    tile[cl][dl] = (int8_t)(int)fq_inti(v, iscv, 127.f);
  }
  __syncthreads();
  #pragma unroll 4
  for (int i = 0; i < 16; i++) {
    int dl = (threadIdx.x >> 6) * 16 + i;
    int cl = threadIdx.x & 63;
    int8_t q = tile[cl][dl];
    g_vT[(kvh * ND + d0 + dl) * NC + c0 + cl] = q;
    int s = (int)q;
    #pragma unroll
    for (int o = 32; o > 0; o >>= 1) s += __shfl_down(s, o, 64);
    if (cl == 0) atomicAdd(&g_colsumV[kvh * ND + d0 + dl], s);
  }
}
__global__ __launch_bounds__(256) void k_ckcv(const float* cache_k, const float* cache_v,
                                              const float* vlin) {
  int b = blockIdx.x;
  if (b < 512) cvT_part(cache_v, vlin, b);
  else         ck_tail_part(cache_k, b - 512, 768);
}

// ---------- attention ----------
DEV float qk_smul() {
  float se = sc16(g_slots[SL_QEMB]);
  float s8 = fmaxf(32767.f * se, 1e-8f) / 127.f;
  float sck = fmaxf(fmaxf(g_slots[SL_KEMB], g_slots[SL_CKT]), 1e-8f) / 32767.f;
  return s8 * sck * 0.08838834764831845f;
}

// pass 1: K-in-regs (64-col chunks). block=(hg,chunk,rowq), 4 waves = 4 q-heads.
__global__ __launch_bounds__(256, 4) void k_attn1(const float* __restrict__ mask) {
  int b = blockIdx.x;
  int chunk = b & 63, rowq = (b >> 6) & 3, hg = b >> 8;
  int wave = threadIdx.x >> 6, lane = threadIdx.x & 63;
  int h = (hg << 2) + wave;
  int r = lane & 15, kg = lane >> 4;
  int kvbase = hg << 12;
  float smul = qk_smul();
  v4i B[4][4];
  #pragma unroll
  for (int j = 0; j < 4; j++) {
    int off = (kvbase + (chunk << 6) + (j << 4) + r) * ND + (kg << 4);
    B[j][0] = *(const v4i*)(g_khi + off);
    B[j][1] = *(const v4i*)(g_khi + off + 64);
    B[j][2] = *(const v4i*)(g_klo + off);
    B[j][3] = *(const v4i*)(g_klo + off + 64);
  }
  float amax = 0.f;
  int s0 = rowq << 8;
  for (int it = 0; it < 16; it++, s0 += 16) {
    const int8_t* qp = g_q8 + ((h << 10) + s0 + r) * ND + (kg << 4);
    v4i a0 = *(const v4i*)qp, a1 = *(const v4i*)(qp + 64);
    int rs[4];
    #pragma unroll
    for (int t = 0; t < 4; t++) rs[t] = g_rowsumQ[(h << 10) + s0 + (kg << 2) + t] << 7;
    const float* mrow = mask + (s0 + (kg << 2)) * NC + (chunk << 6) + r;
    float mx[4] = {-__builtin_inff(), -__builtin_inff(), -__builtin_inff(), -__builtin_inff()};
    #pragma unroll
    for (int j = 0; j < 4; j++) {
      v4i z = {0,0,0,0};
      v4i hi = __builtin_amdgcn_mfma_i32_16x16x64_i8(a0, B[j][0], z, 0, 0, 0);
      hi = __builtin_amdgcn_mfma_i32_16x16x64_i8(a1, B[j][1], hi, 0, 0, 0);
      v4i lo = __builtin_amdgcn_mfma_i32_16x16x64_i8(a0, B[j][2], z, 0, 0, 0);
      lo = __builtin_amdgcn_mfma_i32_16x16x64_i8(a1, B[j][3], lo, 0, 0, 0);
      #pragma unroll
      for (int t = 0; t < 4; t++) {
        int Li = (hi[t] << 8) + lo[t] + rs[t];
        float L = (float)Li * smul + mrow[t * NC + (j << 4)];
        mx[t] = fmaxf(mx[t], L);
        amax = fmaxf(amax, fabsf(L));
      }
    }
    #pragma unroll
    for (int o = 1; o <= 8; o <<= 1) {
      #pragma unroll
      for (int t = 0; t < 4; t++) mx[t] = fmaxf(mx[t], __shfl_xor(mx[t], o));
    }
    if (r == 0) {
      #pragma unroll
      for (int t = 0; t < 4; t++)
        g_LmaxP[chunk][(h << 10) + s0 + (kg << 2) + t] = mx[t];
    }
  }
  amax = block_reduce_max(amax);
  if (threadIdx.x == 0) atomicMax((unsigned int*)&g_slots[SL_LAM], __float_as_uint(amax));
}

// combine per-row max partials
__global__ __launch_bounds__(256) void k_rowmax() {
  int row = blockIdx.x * 256 + threadIdx.x;
  float m = -__builtin_inff();
  #pragma unroll 8
  for (int p = 0; p < 64; p++) m = fmaxf(m, g_LmaxP[p][row]);
  g_Lmax[row] = m;
}

// pass 2: K-in-regs, materialize int16 codes + per-chunk sum-exp partials
__global__ __launch_bounds__(256, 4) void k_attn2(const float* __restrict__ mask) {
  int b = blockIdx.x;
  int chunk = b & 63, rowq = (b >> 6) & 3, hg = b >> 8;
  int wave = threadIdx.x >> 6, lane = threadIdx.x & 63;
  int h = (hg << 2) + wave;
  int r = lane & 15, kg = lane >> 4;
  int kvbase = hg << 12;
  float smul = qk_smul();
  float sL = sc16(g_slots[SL_LAM]);
  float invsL = 1.0f / sL;
  v4i B[4][4];
  #pragma unroll
  for (int j = 0; j < 4; j++) {
    int off = (kvbase + (chunk << 6) + (j << 4) + r) * ND + (kg << 4);
    B[j][0] = *(const v4i*)(g_khi + off);
    B[j][1] = *(const v4i*)(g_khi + off + 64);
    B[j][2] = *(const v4i*)(g_klo + off);
    B[j][3] = *(const v4i*)(g_klo + off + 64);
  }
  int s0 = rowq << 8;
  for (int it = 0; it < 16; it++, s0 += 16) {
    const int8_t* qp = g_q8 + ((h << 10) + s0 + r) * ND + (kg << 4);
    v4i a0 = *(const v4i*)qp, a1 = *(const v4i*)(qp + 64);
    int rs[4];
    float mc[4];
    #pragma unroll
    for (int t = 0; t < 4; t++) {
      int row = (h << 10) + s0 + (kg << 2) + t;
      rs[t] = g_rowsumQ[row] << 7;
      mc[t] = fminf(fmaxf(rintf(g_Lmax[row] * invsL), -32768.f), 32767.f);
    }
    const float* mrow = mask + (s0 + (kg << 2)) * NC + (chunk << 6) + r;
    unsigned short* pbase = g_L16 + (((h << 6) + chunk) << 16) + ((s0 + (kg << 2)) << 6) + r;
    float sm[4] = {0.f, 0.f, 0.f, 0.f};
    #pragma unroll
    for (int j = 0; j < 4; j++) {
      v4i z = {0,0,0,0};
      v4i hi = __builtin_amdgcn_mfma_i32_16x16x64_i8(a0, B[j][0], z, 0, 0, 0);
      hi = __builtin_amdgcn_mfma_i32_16x16x64_i8(a1, B[j][1], hi, 0, 0, 0);
      v4i lo = __builtin_amdgcn_mfma_i32_16x16x64_i8(a0, B[j][2], z, 0, 0, 0);
      lo = __builtin_amdgcn_mfma_i32_16x16x64_i8(a1, B[j][3], lo, 0, 0, 0);
      #pragma unroll
      for (int t = 0; t < 4; t++) {
        int Li = (hi[t] << 8) + lo[t] + rs[t];
        float L = (float)Li * smul + mrow[t * NC + (j << 4)];
        float cf = rintf(L * invsL);
        pbase[(t << 6) + (j << 4)] = (unsigned short)(int)cf;
        sm[t] += __expf((cf - mc[t]) * sL);
      }
    }
    #pragma unroll
    for (int o = 1; o <= 8; o <<= 1) {
      #pragma unroll
      for (int t = 0; t < 4; t++) sm[t] += __shfl_xor(sm[t], o);
    }
    if (r == 0) {
      #pragma unroll
      for (int t = 0; t < 4; t++)
        g_LsP[chunk][(h << 10) + s0 + (kg << 2) + t] = sm[t];
    }
  }
}

// combine row sums (fixed order) + global min-sum
__global__ __launch_bounds__(256) void k_minsum() {
  int row = blockIdx.x * 256 + threadIdx.x;
  float sr = 0.f;
  #pragma unroll 8
  for (int p = 0; p < 64; p++) sr += g_LsP[p][row];
  g_Lsum[row] = sr;
  float m = sr;
  #pragma unroll
  for (int o = 32; o > 0; o >>= 1) m = fminf(m, __shfl_down(m, o, 64));
  __shared__ float red[4];
  __syncthreads();
  if ((threadIdx.x & 63) == 0) red[threadIdx.x >> 6] = m;
  __syncthreads();
  if (threadIdx.x == 0) {
    float v = fminf(fminf(red[0], red[1]), fminf(red[2], red[3]));
    atomicMin((unsigned int*)&g_slots[SL_MINSUM], __float_as_uint(v));
  }
}

// pass 3: P from codes -> PV (int MFMA), fused output absmax.
// Structural plateau: 64 AGPR acc + ~60 VGPR -> 4 waves/SIMD hard cap;
// r6 prefetch, r8 (256,8) coercion, r9 cb-split all measured <= this form.
__global__ __launch_bounds__(256, 4) void k_attn3() {
  int h = blockIdx.x >> 6;
  int s0 = (blockIdx.x & 63) << 4;
  int wave = threadIdx.x >> 6, lane = threadIdx.x & 63;
  int r = lane & 15, kg = lane >> 4;
  int kvh = h >> 2;
  float sL = sc16(g_slots[SL_LAM]);
  float invsL = 1.0f / sL;
  float sP = fmaxf(1.0f / g_slots[SL_MINSUM], 1e-8f) / 32767.f;
  float invsP = 1.0f / sP;
  float sV = fmaxf(fmaxf(g_slots[SL_CVT], g_slots[SL_VLIN]), 1e-8f) / 127.f;
  int arow = (h << 10) + s0 + r;
  float mrc = fminf(fmaxf(rintf(g_Lmax[arow] * invsL), -32768.f), 32767.f);
  float rowscale = (1.0f / g_Lsum[arow]) * invsP;
  float Crow = __logf(rowscale) - mrc * sL;
  v4i accH[8], accL[8];
  #pragma unroll
  for (int j = 0; j < 8; j++) { accH[j] = (v4i){0,0,0,0}; accL[j] = (v4i){0,0,0,0}; }
  for (int cb = wave; cb < 64; cb += 4) {
    const unsigned short* cp = g_L16 + (((h << 6) + cb) << 16) + ((s0 + r) << 6) + kg * 16;
    v8s cA = *(const v8s*)cp;
    v8s cB = *(const v8s*)(cp + 8);
    int pq[16];
    #pragma unroll
    for (int j = 0; j < 8; j++) {
      float p = __expf((float)cA[j] * sL + Crow);
      pq[j] = (int)fminf(rintf(p), 32767.f);
    }
    #pragma unroll
    for (int j = 0; j < 8; j++) {
      float p = __expf((float)cB[j] * sL + Crow);
      pq[8 + j] = (int)fminf(rintf(p), 32767.f);
    }
    int hw[4], lw[4];
    #pragma unroll
    for (int w = 0; w < 4; w++) {
      hw[w] = (pq[4*w] >> 8) | ((pq[4*w+1] >> 8) << 8) | ((pq[4*w+2] >> 8) << 16) | ((pq[4*w+3] >> 8) << 24);
      lw[w] = ((pq[4*w] & 255) ^ 128) | (((pq[4*w+1] & 255) ^ 128) << 8)
            | (((pq[4*w+2] & 255) ^ 128) << 16) | (((pq[4*w+3] & 255) ^ 128) << 24);
    }
    v4i paH = {hw[0], hw[1], hw[2], hw[3]};
    v4i paL = {lw[0], lw[1], lw[2], lw[3]};
    #pragma unroll
    for (int j = 0; j < 8; j++) {
      v4i bv = *(const v4i*)(g_vT + (kvh * ND + j * 16 + r) * NC + cb * 64 + kg * 16);
      accH[j] = __builtin_amdgcn_mfma_i32_16x16x64_i8(paH, bv, accH[j], 0, 0, 0);
      accL[j] = __builtin_amdgcn_mfma_i32_16x16x64_i8(paL, bv, accL[j], 0, 0, 0);
    }
  }
  __shared__ int bufH[16][132];
  __shared__ int bufL[16][132];
  for (int e = threadIdx.x; e < 2048; e += 256) {
    bufH[e >> 7][e & 127] = 0;
    bufL[e >> 7][e & 127] = 0;
  }
  __syncthreads();
  #pragma unroll
  for (int j = 0; j < 8; j++) {
    #pragma unroll
    for (int t = 0; t < 4; t++) {
      atomicAdd(&bufH[kg * 4 + t][j * 16 + r], accH[j][t]);
      atomicAdd(&bufL[kg * 4 + t][j * 16 + r], accL[j][t]);
    }
  }
  __syncthreads();
  double scale = (double)sP * (double)sV;
  float am = 0.f;
  for (int e = threadIdx.x; e < 2048; e += 256) {
    int s = e >> 7, d = e & 127;
    double tot = 256.0 * (double)bufH[s][d] + (double)bufL[s][d]
               + 128.0 * (double)g_colsumV[kvh * ND + d];
    float val = (float)(tot * scale);
    g_qlin[((s0 + s) << 11) + (h << 7) + d] = val;
    am = fmaxf(am, fabsf(val));
  }
  am = block_reduce_max(am);
  if (threadIdx.x == 0) atomicMax((unsigned int*)&g_slots[SL_OATT], __float_as_uint(am));
}

extern "C" void kernel_launch(void* const* d_in, const int* in_sizes, int n_in,
                              void* d_out, int out_size, void* d_ws, size_t ws_size,
                              hipStream_t stream) {
  (void)in_sizes; (void)n_in; (void)out_size; (void)d_ws; (void)ws_size;
  const float* x      = (const float*)d_in[0];
  const float* cosb   = (const float*)d_in[1];
  const float* sinb   = (const float*)d_in[2];
  const float* cachek = (const float*)d_in[3];
  const float* cachev = (const float*)d_in[4];
  const float* mask   = (const float*)d_in[5];
  const float* Wq     = (const float*)d_in[6];
  const float* bq     = (const float*)d_in[7];
  const float* Wk     = (const float*)d_in[8];
  const float* bk     = (const float*)d_in[9];
  const float* Wv     = (const float*)d_in[10];
  const float* bv     = (const float*)d_in[11];
  const float* Wo     = (const float*)d_in[12];
  float* outO = (float*)d_out;
  float* outK = outO + NS * NHID;
  float* outV = outK + NS * NKV;

  k_init<<<1, 256, 0, stream>>>();
  k_absmax7<<<4608, 256, 0, stream>>>(x, Wq, Wk, Wv, Wo, cachek, cachev);
  k_quant5<<<3584, 256, 0, stream>>>(x, Wq, Wk, Wv, Wo);
  k_gemm_q<<<dim3(NHID / 64, NS / 64), 256, 0, stream>>>(bq);
  k_gemm_kv<<<dim3(NKV / 64, NS / 64), 256, 0, stream>>>(bk, outK, 0);
  k_gemm_kv<<<dim3(NKV / 64, NS / 64), 256, 0, stream>>>(bv, outV, 1);
  k_ropeB<<<768, 256, 0, stream>>>(outK, cosb, sinb);
  k_ropeC<<<768, 256, 0, stream>>>(outK, cosb, sinb);
  k_ropeD<<<2560, 256, 0, stream>>>(outK, cosb, sinb);
  k_ckcv<<<1280, 256, 0, stream>>>(cachek, cachev, outV);
  k_attn1<<<1024, 256, 0, stream>>>(mask);
  k_rowmax<<<64, 256, 0, stream>>>();
  k_attn2<<<1024, 256, 0, stream>>>(mask);
  k_minsum<<<64, 256, 0, stream>>>();
  k_attn3<<<1024, 256, 0, stream>>>();
  k_quant8_oatt<<<512, 256, 0, stream>>>();
  k_gemm_o<<<dim3(NHID / 64, NS / 64), 256, 0, stream>>>(outO);
}

// Round 13
// 429.433 us; speedup vs baseline: 1.2596x; 1.0726x over previous
//
#include <hip/hip_runtime.h>
#include <stdint.h>

typedef int v4i __attribute__((ext_vector_type(4)));
typedef short v8s __attribute__((ext_vector_type(8)));
#define DEV __device__ __forceinline__

constexpr int NS    = 1024;
constexpr int NHID  = 2048;
constexpr int NHEAD = 16;
constexpr int NKVH  = 4;
constexpr int ND    = 128;
constexpr int NC    = 4096;
constexpr int NKV   = 512;

#define SL_X 0
#define SL_WQ 1
#define SL_WK 2
#define SL_WV 3
#define SL_WO 4
#define SL_Q 5
#define SL_K 6
#define SL_QH1 7
#define SL_QH2 8
#define SL_KH1 9
#define SL_KH2 10
#define SL_QA 11
#define SL_QB 12
#define SL_KA 13
#define SL_KB 14
#define SL_QEMB 15
#define SL_KEMB 16
#define SL_CKT 17
#define SL_CVT 18
#define SL_VLIN 19
#define SL_LAM 20
#define SL_MINSUM 21
#define SL_OATT 22
// raw half-maxes of gemm outputs (d<64 / d>=64 per 128-col head), captured in
// GEMM epilogues; ropeA deleted via max|fq(fq(x))| = fq(fq(max|x|)) identity
#define SL_QM1 23
#define SL_KM1 25

__device__ float g_slots[64];
__device__ int   g_rowsumQ[NHEAD * NS];
__device__ float g_LmaxP[64][NHEAD * NS];
__device__ float g_LsP[64][NHEAD * NS];
__device__ float g_Lmax[NHEAD * NS];
__device__ float g_Lsum[NHEAD * NS];
__device__ int   g_colsumV[NKVH * ND];
__device__ __align__(16) int8_t g_Xq[NS * NHID];
__device__ __align__(16) int8_t g_W1q[NHID * NHID];
__device__ __align__(16) int8_t g_Woq[NHID * NHID];
__device__ __align__(16) int8_t g_Wkq[NKV * NHID];
__device__ __align__(16) int8_t g_Wvq[NKV * NHID];
__device__ __align__(16) float  g_qlin[NS * NHID];
__device__ __align__(16) int8_t g_q8[NHEAD * NS * ND];
__device__ __align__(16) int8_t g_khi[NKVH * NC * ND];
__device__ __align__(16) int8_t g_klo[NKVH * NC * ND];
__device__ __align__(16) int8_t g_vT[NKVH * ND * NC];
__device__ __align__(16) int8_t g_Oq[NS * NHID];
// int16 logit codes, tiled [h][cb=64][s=1024][64 cols] — 64-col chunks keep
// every 128B store line owned by one block (32-col chunks caused 1.7x write
// amplification, R10)
__device__ __align__(16) unsigned short g_L16[NHEAD * 64 * NS * 64];

DEV float sc8(float a)  { return fmaxf(a, 1e-8f) / 127.0f; }
DEV float sc16(float a) { return fmaxf(a, 1e-8f) / 32767.0f; }

DEV float fq_vali(float x, float s, float invs, float qmax) {
  float q = rintf(x * invs);
  q = fminf(fmaxf(q, -qmax - 1.0f), qmax);
  return q * s;
}
DEV float fq_inti(float x, float invs, float qmax) {
  float q = rintf(x * invs);
  return fminf(fmaxf(q, -qmax - 1.0f), qmax);
}

DEV float block_reduce_max(float m) {
  #pragma unroll
  for (int o = 32; o > 0; o >>= 1) m = fmaxf(m, __shfl_down(m, o, 64));
  __shared__ float red[4];
  __syncthreads();
  if ((threadIdx.x & 63) == 0) red[threadIdx.x >> 6] = m;
  __syncthreads();
  return fmaxf(fmaxf(red[0], red[1]), fmaxf(red[2], red[3]));
}

__global__ void k_init() {
  int t = threadIdx.x;
  if (t < 64) g_slots[t] = (t == SL_MINSUM) ? __builtin_inff() : 0.0f;
  g_colsumV[t] = 0;
  g_colsumV[t + 256] = 0;
}

// ---------- fused absmax over 5 raw inputs + cache tails ----------
DEV void absmax_part(const float* __restrict__ in, int n4, int slot, int b0, int nb) {
  float m = 0.0f;
  int stride = nb * 256;
  for (int i = b0 * 256 + threadIdx.x; i < n4; i += stride) {
    float4 v = ((const float4*)in)[i];
    m = fmaxf(m, fmaxf(fmaxf(fabsf(v.x), fabsf(v.y)), fmaxf(fabsf(v.z), fabsf(v.w))));
  }
  m = block_reduce_max(m);
  if (threadIdx.x == 0) atomicMax((unsigned int*)&g_slots[slot], __float_as_uint(m));
}
DEV void absmax_cache_part(const float* __restrict__ src, int slot, int b0, int nb) {
  float m = 0.0f;
  int stride = nb * 256;
  const int n4 = NKVH * 3072 * 32;
  for (int i = b0 * 256 + threadIdx.x; i < n4; i += stride) {
    int d4 = (i & 31) << 2;
    int rc = i >> 5;
    int kvh = rc / 3072, rr = rc - kvh * 3072;
    float4 v = *(const float4*)(src + kvh * (NC * ND) + (1024 + rr) * ND + d4);
    m = fmaxf(m, fmaxf(fmaxf(fabsf(v.x), fabsf(v.y)), fmaxf(fabsf(v.z), fabsf(v.w))));
  }
  m = block_reduce_max(m);
  if (threadIdx.x == 0) atomicMax((unsigned int*)&g_slots[slot], __float_as_uint(m));
}
__global__ __launch_bounds__(256) void k_absmax7(const float* x, const float* wq,
                                                 const float* wk, const float* wv,
                                                 const float* wo, const float* ck,
                                                 const float* cv) {
  int b = blockIdx.x;
  if      (b < 512)  absmax_part(x,  NS*NHID/4,   SL_X,  b,        512);
  else if (b < 1536) absmax_part(wq, NHID*NHID/4, SL_WQ, b - 512,  1024);
  else if (b < 2048) absmax_part(wk, NKV*NHID/4,  SL_WK, b - 1536, 512);
  else if (b < 2560) absmax_part(wv, NKV*NHID/4,  SL_WV, b - 2048, 512);
  else if (b < 3584) absmax_part(wo, NHID*NHID/4, SL_WO, b - 2560, 1024);
  else if (b < 4096) absmax_cache_part(ck, SL_CKT, b - 3584, 512);
  else               absmax_cache_part(cv, SL_CVT, b - 4096, 512);
}

// ---------- fused quantize of x + 4 weights ----------
DEV void quant_part(const float* __restrict__ in, int8_t* __restrict__ out,
                    int n4, int slot, int b0, int nb) {
  float s = sc8(g_slots[slot]);
  float is = 1.0f / s;
  int stride = nb * 256;
  for (int i = b0 * 256 + threadIdx.x; i < n4; i += stride) {
    float4 v = ((const float4*)in)[i];
    char4 q = make_char4((signed char)(int)fq_inti(v.x, is, 127.f),
                         (signed char)(int)fq_inti(v.y, is, 127.f),
                         (signed char)(int)fq_inti(v.z, is, 127.f),
                         (signed char)(int)fq_inti(v.w, is, 127.f));
    ((char4*)out)[i] = q;
  }
}
__global__ __launch_bounds__(256) void k_quant5(const float* x, const float* wq,
                                                const float* wk, const float* wv,
                                                const float* wo) {
  int b = blockIdx.x;
  if      (b < 512)  quant_part(x,  g_Xq,  NS*NHID/4,   SL_X,  b,        512);
  else if (b < 1536) quant_part(wq, g_W1q, NHID*NHID/4, SL_WQ, b - 512,  1024);
  else if (b < 2048) quant_part(wk, g_Wkq, NKV*NHID/4,  SL_WK, b - 1536, 512);
  else if (b < 2560) quant_part(wv, g_Wvq, NKV*NHID/4,  SL_WV, b - 2048, 512);
  else               quant_part(wo, g_Woq, NHID*NHID/4, SL_WO, b - 2560, 1024);
}
__global__ __launch_bounds__(256) void k_quant8_oatt() {
  quant_part(g_qlin, g_Oq, NS*NHID/4, SL_OATT, blockIdx.x, 512);
}

// ---------- int8 GEMM with fused output absmax (+ optional half-column max) ----------
DEV void gemm_body(const int8_t* __restrict__ A, const int8_t* __restrict__ B,
                   const float* __restrict__ bias, float* __restrict__ C,
                   int N, int K, int sa, int sb, int outslot, int halfslot,
                   int n0, int m0b) {
  float scale = sc8(g_slots[sa]) * sc8(g_slots[sb]);
  int wave = threadIdx.x >> 6, lane = threadIdx.x & 63;
  int r = lane & 15, kg = lane >> 4;
  int m0 = m0b + wave * 16;
  const int8_t* ap = A + (m0 + r) * K + kg * 16;
  const int8_t* bp = B + (n0 + r) * K + kg * 16;
  v4i acc[4] = {{0,0,0,0},{0,0,0,0},{0,0,0,0},{0,0,0,0}};
  for (int kb = 0; kb < K; kb += 64) {
    v4i a = *(const v4i*)(ap + kb);
    #pragma unroll
    for (int j = 0; j < 4; j++) {
      v4i bf = *(const v4i*)(bp + j * 16 * K + kb);
      acc[j] = __builtin_amdgcn_mfma_i32_16x16x64_i8(a, bf, acc[j], 0, 0, 0);
    }
  }
  float am = 0.0f;
  #pragma unroll
  for (int j = 0; j < 4; j++) {
    int n = n0 + j * 16 + r;
    float bvf = bias ? bias[n] : 0.0f;
    #pragma unroll
    for (int t = 0; t < 4; t++) {
      int m = m0 + kg * 4 + t;
      float val = (float)acc[j][t] * scale + bvf;
      C[m * N + n] = val;
      am = fmaxf(am, fabsf(val));
    }
  }
  if (outslot >= 0) {
    am = block_reduce_max(am);
    if (threadIdx.x == 0) {
      atomicMax((unsigned int*)&g_slots[outslot], __float_as_uint(am));
      // this block's 64 columns lie entirely in one 64-half of a 128-col head
      if (halfslot >= 0)
        atomicMax((unsigned int*)&g_slots[halfslot + ((n0 >> 6) & 1)], __float_as_uint(am));
    }
  }
}
// fused q+k+v projection: 512 q blocks + 128 k + 128 v in one launch so the
// small kv gemms (128 blocks each) overlap the q gemm instead of idling 3/4
// of the chip twice
__global__ __launch_bounds__(256) void k_gemmQKV(const float* bq, const float* bk,
                                                 const float* bv, float* outK,
                                                 float* outV) {
  int b = blockIdx.x;
  if (b < 512) {
    gemm_body(g_Xq, g_W1q, bq, g_qlin, NHID, NHID, SL_X, SL_WQ, SL_Q, SL_QM1,
              (b & 31) * 64, (b >> 5) * 64);
  } else if (b < 640) {
    int bb = b - 512;
    gemm_body(g_Xq, g_Wkq, bk, outK, NKV, NHID, SL_X, SL_WK, SL_K, SL_KM1,
              (bb & 7) * 64, (bb >> 3) * 64);
  } else {
    int bb = b - 640;
    gemm_body(g_Xq, g_Wvq, bv, outV, NKV, NHID, SL_X, SL_WV, SL_VLIN, -1,
              (bb & 7) * 64, (bb >> 3) * 64);
  }
}
__global__ __launch_bounds__(256) void k_gemm_o(float* C) {
  gemm_body(g_Oq, g_Woq, nullptr, C, NHID, NHID, SL_OATT, SL_WO, -1, -1,
            blockIdx.x * 64, blockIdx.y * 64);
}

// ---------- RoPE chain (ropeA deleted: m1/m2 derived from raw half-maxes) ----------
struct RS8 { float st, ist, st2, ist2, s2, is2, srh, isrh; };

DEV void rope_ab(const float* __restrict__ rowp, const float* __restrict__ cosp,
                 const float* __restrict__ sinp, int d4, const RS8& sc,
                 float* a, float* b) {
  float4 xv = *(const float4*)(rowp + d4);
  int pd = (d4 < 64) ? d4 + 64 : d4 - 64;
  float4 pv = *(const float4*)(rowp + pd);
  float4 cv = *(const float4*)(cosp + d4);
  float4 sv = *(const float4*)(sinp + d4);
  float xs[4] = {xv.x, xv.y, xv.z, xv.w};
  float ps[4] = {pv.x, pv.y, pv.z, pv.w};
  float cs[4] = {cv.x, cv.y, cv.z, cv.w};
  float ss[4] = {sv.x, sv.y, sv.z, sv.w};
  #pragma unroll
  for (int e = 0; e < 4; e++) {
    float v16 = fq_vali(xs[e], sc.st, sc.ist, 32767.f);
    float tp  = fq_vali(fq_vali(ps[e], sc.st, sc.ist, 32767.f), sc.st2, sc.ist2, 32767.f);
    float rh;
    if (d4 < 64) rh = fq_vali(fq_vali(-tp, sc.s2, sc.is2, 32767.f), sc.srh, sc.isrh, 32767.f);
    else         rh = fq_vali(tp, sc.srh, sc.isrh, 32767.f);
    a[e] = v16 * cs[e];
    b[e] = rh * ss[e];
  }
}

// m_half = max|fq(fq(x, st), st2)| over a half = fq(fq(max|x|)) — fq∘fq is
// monotone and odd (rint half-even symmetric; clamps inactive since
// |x| <= absmax = 32767*st), so the identity is exact.
DEV RS8 mk_rs(int slotT, int slotM1) {
  RS8 sc;
  sc.st = sc16(g_slots[slotT]);
  sc.ist = 1.0f / sc.st;
  sc.st2 = fmaxf(32767.f * sc.st, 1e-8f) / 32767.f;
  sc.ist2 = 1.0f / sc.st2;
  float m1 = fq_vali(fq_vali(g_slots[slotM1],     sc.st, sc.ist, 32767.f), sc.st2, sc.ist2, 32767.f);
  float m2 = fq_vali(fq_vali(g_slots[slotM1 + 1], sc.st, sc.ist, 32767.f), sc.st2, sc.ist2, 32767.f);
  sc.s2 = sc16(m2);
  sc.is2 = 1.0f / sc.s2;
  sc.srh = fmaxf(fmaxf(m1, 32767.f * sc.s2), 1e-8f) / 32767.f;
  sc.isrh = 1.0f / sc.srh;
  return sc;
}

DEV void ropeBC_part(const float* __restrict__ src, const float* __restrict__ cosb,
                     const float* __restrict__ sinb, int nrows, int lgH, const RS8& sc,
                     int mode, float sa, float isa, float sb, float isb,
                     int o1, int o2, int b0, int nb) {
  int n4 = nrows * 32;
  float m1 = 0.f, m2 = 0.f;
  int stride = nb * 256;
  for (int i = b0 * 256 + threadIdx.x; i < n4; i += stride) {
    int d4 = (i & 31) << 2;
    int rowg = i >> 5;
    int s = rowg >> lgH;
    float a[4], b[4];
    rope_ab(src + (rowg << 7), cosb + (s << 7), sinb + (s << 7), d4, sc, a, b);
    if (mode == 0) {
      #pragma unroll
      for (int e = 0; e < 4; e++) { m1 = fmaxf(m1, fabsf(a[e])); m2 = fmaxf(m2, fabsf(b[e])); }
    } else {
      #pragma unroll
      for (int e = 0; e < 4; e++) {
        float ev = fq_vali(a[e], sa, isa, 32767.f) + fq_vali(b[e], sb, isb, 32767.f);
        m1 = fmaxf(m1, fabsf(ev));
      }
    }
  }
  m1 = block_reduce_max(m1);
  if (threadIdx.x == 0) atomicMax((unsigned int*)&g_slots[o1], __float_as_uint(m1));
  if (mode == 0) {
    m2 = block_reduce_max(m2);
    if (threadIdx.x == 0) atomicMax((unsigned int*)&g_slots[o2], __float_as_uint(m2));
  }
}

__global__ __launch_bounds__(256) void k_ropeB(const float* klin, const float* cosb, const float* sinb) {
  int b = blockIdx.x;
  if (b < 512) {
    RS8 sc = mk_rs(SL_Q, SL_QM1);
    ropeBC_part(g_qlin, cosb, sinb, NHEAD * NS, 4, sc, 0, 0.f, 0.f, 0.f, 0.f, SL_QA, SL_QB, b, 512);
  } else {
    RS8 sc = mk_rs(SL_K, SL_KM1);
    ropeBC_part(klin, cosb, sinb, NKVH * NS, 2, sc, 0, 0.f, 0.f, 0.f, 0.f, SL_KA, SL_KB, b - 512, 256);
  }
}
__global__ __launch_bounds__(256) void k_ropeC(const float* klin, const float* cosb, const float* sinb) {
  int b = blockIdx.x;
  if (b < 512) {
    RS8 sc = mk_rs(SL_Q, SL_QM1);
    float sa = sc16(g_slots[SL_QA]), sb = sc16(g_slots[SL_QB]);
    ropeBC_part(g_qlin, cosb, sinb, NHEAD * NS, 4, sc, 1, sa, 1.0f/sa, sb, 1.0f/sb,
                SL_QEMB, 0, b, 512);
  } else {
    RS8 sc = mk_rs(SL_K, SL_KM1);
    float sa = sc16(g_slots[SL_KA]), sb = sc16(g_slots[SL_KB]);
    ropeBC_part(klin, cosb, sinb, NKVH * NS, 2, sc, 1, sa, 1.0f/sa, sb, 1.0f/sb,
                SL_KEMB, 0, b - 512, 256);
  }
}

DEV void ropeD_part(const float* __restrict__ src, const float* __restrict__ cosb,
                    const float* __restrict__ sinb, int lgH, const RS8& sc,
                    float sa, float isa, float sb, float isb,
                    int isQ, float se, float ise, float isq, int b0) {
  int rowg = b0 * 8 + (threadIdx.x >> 5);
  int lane32 = threadIdx.x & 31;
  int d4 = lane32 << 2;
  int hmask = (1 << lgH) - 1;
  int h = rowg & hmask, s = rowg >> lgH;
  float a[4], b[4];
  rope_ab(src + (rowg << 7), cosb + (s << 7), sinb + (s << 7), d4, sc, a, b);
  if (isQ) {
    int rs = 0;
    signed char qb[4];
    #pragma unroll
    for (int e = 0; e < 4; e++) {
      float ev = fq_vali(a[e], sa, isa, 32767.f) + fq_vali(b[e], sb, isb, 32767.f);
      float e16 = fq_vali(ev, se, ise, 32767.f);
      float qf = fq_inti(e16, isq, 127.f);
      qb[e] = (signed char)(int)qf;
      rs += (int)qf;
    }
    *(char4*)(g_q8 + ((h << 10) + s) * ND + d4) = make_char4(qb[0], qb[1], qb[2], qb[3]);
    #pragma unroll
    for (int o = 16; o > 0; o >>= 1) rs += __shfl_down(rs, o, 32);
    if (lane32 == 0) g_rowsumQ[(h << 10) + s] = rs;
  } else {
    signed char qh[4], ql[4];
    #pragma unroll
    for (int e = 0; e < 4; e++) {
      float ev = fq_vali(a[e], sa, isa, 32767.f) + fq_vali(b[e], sb, isb, 32767.f);
      int q = (int)fq_inti(ev, isq, 32767.f);
      qh[e] = (signed char)(q >> 8);
      ql[e] = (signed char)((q & 255) - 128);
    }
    int off = (h * NC + 3072 + s) * ND + d4;
    *(char4*)(g_khi + off) = make_char4(qh[0], qh[1], qh[2], qh[3]);
    *(char4*)(g_klo + off) = make_char4(ql[0], ql[1], ql[2], ql[3]);
  }
}

// ---------- ck tail quantize + cv transpose (+colsum) ----------
DEV void ck_tail_part(const float* __restrict__ cache_k, int b0, int nb) {
  float sck = fmaxf(fmaxf(g_slots[SL_KEMB], g_slots[SL_CKT]), 1e-8f) / 32767.f;
  float isck = 1.0f / sck;
  int n4 = NKVH * 3072 * 32;
  int stride = nb * 256;
  for (int i = b0 * 256 + threadIdx.x; i < n4; i += stride) {
    int d4 = (i & 31) << 2;
    int rc = i >> 5;
    int kvh = rc / 3072, rr = rc - kvh * 3072;
    float4 v = *(const float4*)(cache_k + kvh * (NC * ND) + (1024 + rr) * ND + d4);
    float xs[4] = {v.x, v.y, v.z, v.w};
    signed char qh[4], ql[4];
    #pragma unroll
    for (int e = 0; e < 4; e++) {
      int q = (int)fq_inti(xs[e], isck, 32767.f);
      qh[e] = (signed char)(q >> 8);
      ql[e] = (signed char)((q & 255) - 128);
    }
    int off = (kvh * NC + rr) * ND + d4;
    *(char4*)(g_khi + off) = make_char4(qh[0], qh[1], qh[2], qh[3]);
    *(char4*)(g_klo + off) = make_char4(ql[0], ql[1], ql[2], ql[3]);
  }
}
DEV void cvT_part(const float* __restrict__ cache_v, const float* __restrict__ vlin, int bb) {
  float scv = fmaxf(fmaxf(g_slots[SL_CVT], g_slots[SL_VLIN]), 1e-8f) / 127.f;
  float iscv = 1.0f / scv;
  int kvh = bb >> 7;
  int cblk = (bb >> 1) & 63;
  int dblk = bb & 1;
  int c0 = cblk * 64, d0 = dblk * 64;
  __shared__ int8_t tile[64][68];
  #pragma unroll 4
  for (int i = 0; i < 16; i++) {
    int cl = (threadIdx.x >> 6) * 16 + i;
    int dl = threadIdx.x & 63;
    int c = c0 + cl, d = d0 + dl;
    float v = (c < 3072) ? cache_v[kvh * (NC * ND) + (1024 + c) * ND + d]
                         : vlin[(c - 3072) * NKV + kvh * ND + d];
    tile[cl][dl] = (int8_t)(int)fq_inti(v, iscv, 127.f);
  }
  __syncthreads();
  #pragma unroll 4
  for (int i = 0; i < 16; i++) {
    int dl = (threadIdx.x >> 6) * 16 + i;
    int cl = threadIdx.x & 63;
    int8_t q = tile[cl][dl];
    g_vT[(kvh * ND + d0 + dl) * NC + c0 + cl] = q;
    int s = (int)q;
    #pragma unroll
    for (int o = 32; o > 0; o >>= 1) s += __shfl_down(s, o, 64);
    if (cl == 0) atomicAdd(&g_colsumV[kvh * ND + d0 + dl], s);
  }
}

// fused ropeD + ck/cv requantize: independent work, one launch (3840 blocks)
__global__ __launch_bounds__(256) void k_ropeDckcv(const float* klin,
                                                   const float* cosb, const float* sinb,
                                                   const float* cachek, const float* cachev,
                                                   const float* vlin) {
  int b = blockIdx.x;
  if (b < 2048) {
    RS8 sc = mk_rs(SL_Q, SL_QM1);
    float sa = sc16(g_slots[SL_QA]), sb = sc16(g_slots[SL_QB]);
    float se = sc16(g_slots[SL_QEMB]);
    float s8 = fmaxf(32767.f * se, 1e-8f) / 127.f;
    ropeD_part(g_qlin, cosb, sinb, 4, sc, sa, 1.0f/sa, sb, 1.0f/sb,
               1, se, 1.0f/se, 1.0f/s8, b);
  } else if (b < 2560) {
    RS8 sc = mk_rs(SL_K, SL_KM1);
    float sa = sc16(g_slots[SL_KA]), sb = sc16(g_slots[SL_KB]);
    float sck = fmaxf(fmaxf(g_slots[SL_KEMB], g_slots[SL_CKT]), 1e-8f) / 32767.f;
    ropeD_part(klin, cosb, sinb, 2, sc, sa, 1.0f/sa, sb, 1.0f/sb,
               0, 1.f, 1.f, 1.0f/sck, b - 2048);
  } else if (b < 3072) {
    cvT_part(cachev, vlin, b - 2560);
  } else {
    ck_tail_part(cachek, b - 3072, 768);
  }
}

// ---------- attention ----------
DEV float qk_smul() {
  float se = sc16(g_slots[SL_QEMB]);
  float s8 = fmaxf(32767.f * se, 1e-8f) / 127.f;
  float sck = fmaxf(fmaxf(g_slots[SL_KEMB], g_slots[SL_CKT]), 1e-8f) / 32767.f;
  return s8 * sck * 0.08838834764831845f;
}

// pass 1: K-in-regs (64-col chunks). block=(hg,chunk,rowq), 4 waves = 4 q-heads.
__global__ __launch_bounds__(256, 4) void k_attn1(const float* __restrict__ mask) {
  int b = blockIdx.x;
  int chunk = b & 63, rowq = (b >> 6) & 3, hg = b >> 8;
  int wave = threadIdx.x >> 6, lane = threadIdx.x & 63;
  int h = (hg << 2) + wave;
  int r = lane & 15, kg = lane >> 4;
  int kvbase = hg << 12;
  float smul = qk_smul();
  v4i B[4][4];
  #pragma unroll
  for (int j = 0; j < 4; j++) {
    int off = (kvbase + (chunk << 6) + (j << 4) + r) * ND + (kg << 4);
    B[j][0] = *(const v4i*)(g_khi + off);
    B[j][1] = *(const v4i*)(g_khi + off + 64);
    B[j][2] = *(const v4i*)(g_klo + off);
    B[j][3] = *(const v4i*)(g_klo + off + 64);
  }
  float amax = 0.f;
  int s0 = rowq << 8;
  for (int it = 0; it < 16; it++, s0 += 16) {
    const int8_t* qp = g_q8 + ((h << 10) + s0 + r) * ND + (kg << 4);
    v4i a0 = *(const v4i*)qp, a1 = *(const v4i*)(qp + 64);
    int rs[4];
    #pragma unroll
    for (int t = 0; t < 4; t++) rs[t] = g_rowsumQ[(h << 10) + s0 + (kg << 2) + t] << 7;
    const float* mrow = mask + (s0 + (kg << 2)) * NC + (chunk << 6) + r;
    float mx[4] = {-__builtin_inff(), -__builtin_inff(), -__builtin_inff(), -__builtin_inff()};
    #pragma unroll
    for (int j = 0; j < 4; j++) {
      v4i z = {0,0,0,0};
      v4i hi = __builtin_amdgcn_mfma_i32_16x16x64_i8(a0, B[j][0], z, 0, 0, 0);
      hi = __builtin_amdgcn_mfma_i32_16x16x64_i8(a1, B[j][1], hi, 0, 0, 0);
      v4i lo = __builtin_amdgcn_mfma_i32_16x16x64_i8(a0, B[j][2], z, 0, 0, 0);
      lo = __builtin_amdgcn_mfma_i32_16x16x64_i8(a1, B[j][3], lo, 0, 0, 0);
      #pragma unroll
      for (int t = 0; t < 4; t++) {
        int Li = (hi[t] << 8) + lo[t] + rs[t];
        float L = (float)Li * smul + mrow[t * NC + (j << 4)];
        mx[t] = fmaxf(mx[t], L);
        amax = fmaxf(amax, fabsf(L));
      }
    }
    #pragma unroll
    for (int o = 1; o <= 8; o <<= 1) {
      #pragma unroll
      for (int t = 0; t < 4; t++) mx[t] = fmaxf(mx[t], __shfl_xor(mx[t], o));
    }
    if (r == 0) {
      #pragma unroll
      for (int t = 0; t < 4; t++)
        g_LmaxP[chunk][(h << 10) + s0 + (kg << 2) + t] = mx[t];
    }
  }
  amax = block_reduce_max(amax);
  if (threadIdx.x == 0) atomicMax((unsigned int*)&g_slots[SL_LAM], __float_as_uint(amax));
}

// combine per-row max partials
__global__ __launch_bounds__(256) void k_rowmax() {
  int row = blockIdx.x * 256 + threadIdx.x;
  float m = -__builtin_inff();
  #pragma unroll 8
  for (int p = 0; p < 64; p++) m = fmaxf(m, g_LmaxP[p][row]);
  g_Lmax[row] = m;
}

// pass 2: K-in-regs, materialize int16 codes + per-chunk sum-exp partials
__global__ __launch_bounds__(256, 4) void k_attn2(const float* __restrict__ mask) {
  int b = blockIdx.x;
  int chunk = b & 63, rowq = (b >> 6) & 3, hg = b >> 8;
  int wave = threadIdx.x >> 6, lane = threadIdx.x & 63;
  int h = (hg << 2) + wave;
  int r = lane & 15, kg = lane >> 4;
  int kvbase = hg << 12;
  float smul = qk_smul();
  float sL = sc16(g_slots[SL_LAM]);
  float invsL = 1.0f / sL;
  v4i B[4][4];
  #pragma unroll
  for (int j = 0; j < 4; j++) {
    int off = (kvbase + (chunk << 6) + (j << 4) + r) * ND + (kg << 4);
    B[j][0] = *(const v4i*)(g_khi + off);
    B[j][1] = *(const v4i*)(g_khi + off + 64);
    B[j][2] = *(const v4i*)(g_klo + off);
    B[j][3] = *(const v4i*)(g_klo + off + 64);
  }
  int s0 = rowq << 8;
  for (int it = 0; it < 16; it++, s0 += 16) {
    const int8_t* qp = g_q8 + ((h << 10) + s0 + r) * ND + (kg << 4);
    v4i a0 = *(const v4i*)qp, a1 = *(const v4i*)(qp + 64);
    int rs[4];
    float mc[4];
    #pragma unroll
    for (int t = 0; t < 4; t++) {
      int row = (h << 10) + s0 + (kg << 2) + t;
      rs[t] = g_rowsumQ[row] << 7;
      mc[t] = fminf(fmaxf(rintf(g_Lmax[row] * invsL), -32768.f), 32767.f);
    }
    const float* mrow = mask + (s0 + (kg << 2)) * NC + (chunk << 6) + r;
    unsigned short* pbase = g_L16 + (((h << 6) + chunk) << 16) + ((s0 + (kg << 2)) << 6) + r;
    float sm[4] = {0.f, 0.f, 0.f, 0.f};
    #pragma unroll
    for (int j = 0; j < 4; j++) {
      v4i z = {0,0,0,0};
      v4i hi = __builtin_amdgcn_mfma_i32_16x16x64_i8(a0, B[j][0], z, 0, 0, 0);
      hi = __builtin_amdgcn_mfma_i32_16x16x64_i8(a1, B[j][1], hi, 0, 0, 0);
      v4i lo = __builtin_amdgcn_mfma_i32_16x16x64_i8(a0, B[j][2], z, 0, 0, 0);
      lo = __builtin_amdgcn_mfma_i32_16x16x64_i8(a1, B[j][3], lo, 0, 0, 0);
      #pragma unroll
      for (int t = 0; t < 4; t++) {
        int Li = (hi[t] << 8) + lo[t] + rs[t];
        float L = (float)Li * smul + mrow[t * NC + (j << 4)];
        float cf = rintf(L * invsL);
        pbase[(t << 6) + (j << 4)] = (unsigned short)(int)cf;
        sm[t] += __expf((cf - mc[t]) * sL);
      }
    }
    #pragma unroll
    for (int o = 1; o <= 8; o <<= 1) {
      #pragma unroll
      for (int t = 0; t < 4; t++) sm[t] += __shfl_xor(sm[t], o);
    }
    if (r == 0) {
      #pragma unroll
      for (int t = 0; t < 4; t++)
        g_LsP[chunk][(h << 10) + s0 + (kg << 2) + t] = sm[t];
    }
  }
}

// combine row sums (fixed order) + global min-sum
__global__ __launch_bounds__(256) void k_minsum() {
  int row = blockIdx.x * 256 + threadIdx.x;
  float sr = 0.f;
  #pragma unroll 8
  for (int p = 0; p < 64; p++) sr += g_LsP[p][row];
  g_Lsum[row] = sr;
  float m = sr;
  #pragma unroll
  for (int o = 32; o > 0; o >>= 1) m = fminf(m, __shfl_down(m, o, 64));
  __shared__ float red[4];
  __syncthreads();
  if ((threadIdx.x & 63) == 0) red[threadIdx.x >> 6] = m;
  __syncthreads();
  if (threadIdx.x == 0) {
    float v = fminf(fminf(red[0], red[1]), fminf(red[2], red[3]));
    atomicMin((unsigned int*)&g_slots[SL_MINSUM], __float_as_uint(v));
  }
}

// pass 3: P from codes -> PV (int MFMA), fused output absmax.
// Structural plateau: 64 AGPR acc + ~60 VGPR -> 4 waves/SIMD hard cap;
// r6 prefetch, r8 (256,8) coercion, r9 cb-split all measured <= this form.
__global__ __launch_bounds__(256, 4) void k_attn3() {
  int h = blockIdx.x >> 6;
  int s0 = (blockIdx.x & 63) << 4;
  int wave = threadIdx.x >> 6, lane = threadIdx.x & 63;
  int r = lane & 15, kg = lane >> 4;
  int kvh = h >> 2;
  float sL = sc16(g_slots[SL_LAM]);
  float invsL = 1.0f / sL;
  float sP = fmaxf(1.0f / g_slots[SL_MINSUM], 1e-8f) / 32767.f;
  float invsP = 1.0f / sP;
  float sV = fmaxf(fmaxf(g_slots[SL_CVT], g_slots[SL_VLIN]), 1e-8f) / 127.f;
  int arow = (h << 10) + s0 + r;
  float mrc = fminf(fmaxf(rintf(g_Lmax[arow] * invsL), -32768.f), 32767.f);
  float rowscale = (1.0f / g_Lsum[arow]) * invsP;
  float Crow = __logf(rowscale) - mrc * sL;
  v4i accH[8], accL[8];
  #pragma unroll
  for (int j = 0; j < 8; j++) { accH[j] = (v4i){0,0,0,0}; accL[j] = (v4i){0,0,0,0}; }
  for (int cb = wave; cb < 64; cb += 4) {
    const unsigned short* cp = g_L16 + (((h << 6) + cb) << 16) + ((s0 + r) << 6) + kg * 16;
    v8s cA = *(const v8s*)cp;
    v8s cB = *(const v8s*)(cp + 8);
    int pq[16];
    #pragma unroll
    for (int j = 0; j < 8; j++) {
      float p = __expf((float)cA[j] * sL + Crow);
      pq[j] = (int)fminf(rintf(p), 32767.f);
    }
    #pragma unroll
    for (int j = 0; j < 8; j++) {
      float p = __expf((float)cB[j] * sL + Crow);
      pq[8 + j] = (int)fminf(rintf(p), 32767.f);
    }
    int hw[4], lw[4];
    #pragma unroll
    for (int w = 0; w < 4; w++) {
      hw[w] = (pq[4*w] >> 8) | ((pq[4*w+1] >> 8) << 8) | ((pq[4*w+2] >> 8) << 16) | ((pq[4*w+3] >> 8) << 24);
      lw[w] = ((pq[4*w] & 255) ^ 128) | (((pq[4*w+1] & 255) ^ 128) << 8)
            | (((pq[4*w+2] & 255) ^ 128) << 16) | (((pq[4*w+3] & 255) ^ 128) << 24);
    }
    v4i paH = {hw[0], hw[1], hw[2], hw[3]};
    v4i paL = {lw[0], lw[1], lw[2], lw[3]};
    #pragma unroll
    for (int j = 0; j < 8; j++) {
      v4i bv = *(const v4i*)(g_vT + (kvh * ND + j * 16 + r) * NC + cb * 64 + kg * 16);
      accH[j] = __builtin_amdgcn_mfma_i32_16x16x64_i8(paH, bv, accH[j], 0, 0, 0);
      accL[j] = __builtin_amdgcn_mfma_i32_16x16x64_i8(paL, bv, accL[j], 0, 0, 0);
    }
  }
  __shared__ int bufH[16][132];
  __shared__ int bufL[16][132];
  for (int e = threadIdx.x; e < 2048; e += 256) {
    bufH[e >> 7][e & 127] = 0;
    bufL[e >> 7][e & 127] = 0;
  }
  __syncthreads();
  #pragma unroll
  for (int j = 0; j < 8; j++) {
    #pragma unroll
    for (int t = 0; t < 4; t++) {
      atomicAdd(&bufH[kg * 4 + t][j * 16 + r], accH[j][t]);
      atomicAdd(&bufL[kg * 4 + t][j * 16 + r], accL[j][t]);
    }
  }
  __syncthreads();
  double scale = (double)sP * (double)sV;
  float am = 0.f;
  for (int e = threadIdx.x; e < 2048; e += 256) {
    int s = e >> 7, d = e & 127;
    double tot = 256.0 * (double)bufH[s][d] + (double)bufL[s][d]
               + 128.0 * (double)g_colsumV[kvh * ND + d];
    float val = (float)(tot * scale);
    g_qlin[((s0 + s) << 11) + (h << 7) + d] = val;
    am = fmaxf(am, fabsf(val));
  }
  am = block_reduce_max(am);
  if (threadIdx.x == 0) atomicMax((unsigned int*)&g_slots[SL_OATT], __float_as_uint(am));
}

extern "C" void kernel_launch(void* const* d_in, const int* in_sizes, int n_in,
                              void* d_out, int out_size, void* d_ws, size_t ws_size,
                              hipStream_t stream) {
  (void)in_sizes; (void)n_in; (void)out_size; (void)d_ws; (void)ws_size;
  const float* x      = (const float*)d_in[0];
  const float* cosb   = (const float*)d_in[1];
  const float* sinb   = (const float*)d_in[2];
  const float* cachek = (const float*)d_in[3];
  const float* cachev = (const float*)d_in[4];
  const float* mask   = (const float*)d_in[5];
  const float* Wq     = (const float*)d_in[6];
  const float* bq     = (const float*)d_in[7];
  const float* Wk     = (const float*)d_in[8];
  const float* bk     = (const float*)d_in[9];
  const float* Wv     = (const float*)d_in[10];
  const float* bv     = (const float*)d_in[11];
  const float* Wo     = (const float*)d_in[12];
  float* outO = (float*)d_out;
  float* outK = outO + NS * NHID;
  float* outV = outK + NS * NKV;

  k_init<<<1, 256, 0, stream>>>();
  k_absmax7<<<4608, 256, 0, stream>>>(x, Wq, Wk, Wv, Wo, cachek, cachev);
  k_quant5<<<3584, 256, 0, stream>>>(x, Wq, Wk, Wv, Wo);
  k_gemmQKV<<<768, 256, 0, stream>>>(bq, bk, bv, outK, outV);
  k_ropeB<<<768, 256, 0, stream>>>(outK, cosb, sinb);
  k_ropeC<<<768, 256, 0, stream>>>(outK, cosb, sinb);
  k_ropeDckcv<<<3840, 256, 0, stream>>>(outK, cosb, sinb, cachek, cachev, outV);
  k_attn1<<<1024, 256, 0, stream>>>(mask);
  k_rowmax<<<64, 256, 0, stream>>>();
  k_attn2<<<1024, 256, 0, stream>>>(mask);
  k_minsum<<<64, 256, 0, stream>>>();
  k_attn3<<<1024, 256, 0, stream>>>();
  k_quant8_oatt<<<512, 256, 0, stream>>>();
  k_gemm_o<<<dim3(NHID / 64, NS / 64), 256, 0, stream>>>(outO);
}